// Round 13
// baseline (361.482 us; speedup 1.0000x reference)
//
#include <hip/hip_runtime.h>
#include <math.h>

#define LDIM 2048
#define DDIM 128
#define BDIM 16
#define FDIM 100
// Split-K bf16 GEMM: A' = [AH | AL | AH], B' = [BH | BH | BL], K = 384.
// Panel layout per (batch,row-panel): [48 koct][128 row][8 elems] bf16 -> 16KB-contiguous K-tiles.
#define PANEL_U16 (48 * 1024)
// conv-as-GEMM: K = 3*128 = 384, N = 112 (100 filters padded to 7 tiles of 16)
#define FPAD 112
#define CT 64            // t-rows per conv block

typedef unsigned short u16;
typedef __bf16 bf16x8 __attribute__((ext_vector_type(8)));
typedef float f32x4 __attribute__((ext_vector_type(4)));

__device__ inline unsigned f2bfu(float x) {  // fp32 -> bf16 bits, RNE
  unsigned u = __float_as_uint(x);
  return (u + 0x7FFFu + ((u >> 16) & 1u)) >> 16;
}
__device__ inline unsigned pk2(float a, float b) {
  return f2bfu(a) | (f2bfu(b) << 16);
}
__device__ inline float bfhi(float x) {  // value of the bf16 hi part
  return __uint_as_float(f2bfu(x) << 16);
}

__device__ inline void glds16(const u16* g, u16* l) {
  __builtin_amdgcn_global_load_lds(
      (const __attribute__((address_space(1))) void*)g,
      (__attribute__((address_space(3))) void*)l, 16, 0, 0);
}

__device__ inline void ins3(float w, int idx, float v[3], int id[3]) {
  if (w > v[2]) {
    if (w > v[0]) { v[2]=v[1]; id[2]=id[1]; v[1]=v[0]; id[1]=id[0]; v[0]=w; id[0]=idx; }
    else if (w > v[1]) { v[2]=v[1]; id[2]=id[1]; v[1]=w; id[1]=idx; }
    else { v[2]=w; id[2]=idx; }
  }
}

// Expand fp32 inputs into split-bf16 panel layout (hi/lo), both ctx and main.
__global__ __launch_bounds__(256) void split_convert(const float* __restrict__ ctx,
    const float* __restrict__ mn, u16* __restrict__ ctxS, u16* __restrict__ mnS) {
  const int b = blockIdx.y;
  const int rp = blockIdx.x & 15, og = blockIdx.x >> 4;  // og 0..7
  const int tid = threadIdx.x;
  const int row = tid & 127;
  const int o = og * 2 + (tid >> 7);                     // source k-octet 0..15
  const size_t srcOff = (((size_t)b * LDIM + rp * 128 + row) * DDIM + o * 8);
  const float4 c0 = *(const float4*)(ctx + srcOff);
  const float4 c1 = *(const float4*)(ctx + srcOff + 4);
  const float4 m0 = *(const float4*)(mn + srcOff);
  const float4 m1 = *(const float4*)(mn + srcOff + 4);
  uint4 chi = make_uint4(pk2(c0.x,c0.y), pk2(c0.z,c0.w), pk2(c1.x,c1.y), pk2(c1.z,c1.w));
  uint4 clo = make_uint4(pk2(c0.x-bfhi(c0.x), c0.y-bfhi(c0.y)),
                         pk2(c0.z-bfhi(c0.z), c0.w-bfhi(c0.w)),
                         pk2(c1.x-bfhi(c1.x), c1.y-bfhi(c1.y)),
                         pk2(c1.z-bfhi(c1.z), c1.w-bfhi(c1.w)));
  uint4 mhi = make_uint4(pk2(m0.x,m0.y), pk2(m0.z,m0.w), pk2(m1.x,m1.y), pk2(m1.z,m1.w));
  uint4 mlo = make_uint4(pk2(m0.x-bfhi(m0.x), m0.y-bfhi(m0.y)),
                         pk2(m0.z-bfhi(m0.z), m0.w-bfhi(m0.w)),
                         pk2(m1.x-bfhi(m1.x), m1.y-bfhi(m1.y)),
                         pk2(m1.z-bfhi(m1.z), m1.w-bfhi(m1.w)));
  u16* dA = ctxS + ((size_t)b * 16 + rp) * PANEL_U16;
  u16* dB = mnS  + ((size_t)b * 16 + rp) * PANEL_U16;
  const int base = o * 1024 + row * 8;
  *(uint4*)(dA + base)         = chi;   // koct o      : AH
  *(uint4*)(dA + base + 16384) = clo;   // koct o + 16 : AL
  *(uint4*)(dA + base + 32768) = chi;   // koct o + 32 : AH
  *(uint4*)(dB + base)         = mhi;   // koct o      : BH
  *(uint4*)(dB + base + 16384) = mhi;   // koct o + 16 : BH
  *(uint4*)(dB + base + 32768) = mlo;   // koct o + 32 : BL
}

// W[b][c][m] = ctx.main^T via split-bf16 MFMA (K=384). W is NEVER stored.
// Epilogue: each 64x64 wave-quadrant staged to a 64x65 LDS buffer (overlaid on
// dead As/Bs), reduced by whole waves with ILP-2 chains (2 x 32 independent
// ins3 chains per thread, merged at write). Col chains persist across the two
// rounds (same column, both row-halves) -> 16 col records; rows write per round
// -> 32 row records. Serial walks, no shuffles (R11/R12-proven idiom).
__global__ __launch_bounds__(256) void gemm_mfma(const u16* __restrict__ A,
    const u16* __restrict__ B, unsigned* __restrict__ rowP,
    unsigned* __restrict__ colP) {
  __shared__ __attribute__((aligned(16))) char ldsbuf[33280];
  u16* As = (u16*)ldsbuf;            // 16 KB (main loop)
  u16* Bs = As + 8192;               // 16 KB (main loop)
  float* stg = (float*)ldsbuf;       // epilogue: 2 x 4160 floats (64x65 each)
  const int b = blockIdx.z;
  const int rp = blockIdx.y, mp = blockIdx.x;
  const int tid = threadIdx.x;
  const int w = tid >> 6, lane = tid & 63;
  const int lr = lane & 15, lg = lane >> 4;
  const int wr = w >> 1, wc = w & 1;
  const u16* srcA = A + ((size_t)b * 16 + rp) * PANEL_U16;
  const u16* srcB = B + ((size_t)b * 16 + mp) * PANEL_U16;
  f32x4 acc[4][4];
  const f32x4 zz = {0.f, 0.f, 0.f, 0.f};
  #pragma unroll
  for (int i = 0; i < 4; i++)
    #pragma unroll
    for (int j = 0; j < 4; j++) acc[i][j] = zz;

  for (int kt = 0; kt < 6; kt++) {
    if (kt) __syncthreads();
    const u16* sA = srcA + kt * 8192;
    const u16* sB = srcB + kt * 8192;
    #pragma unroll
    for (int q = 0; q < 4; q++) {
      const int c = q * 256 + w * 64;           // chunk index base for this wave
      glds16(sA + (size_t)(c + lane) * 8, As + c * 8);
      glds16(sB + (size_t)(c + lane) * 8, Bs + c * 8);
    }
    __syncthreads();
    #pragma unroll
    for (int ks = 0; ks < 2; ks++) {
      const int ab = (ks * 4 + lg) * 1024 + (wr * 64 + lr) * 8;
      const int bb = (ks * 4 + lg) * 1024 + (wc * 64 + lr) * 8;
      bf16x8 av[4], bv[4];
      #pragma unroll
      for (int i = 0; i < 4; i++) av[i] = *(const bf16x8*)&As[ab + i * 128];
      #pragma unroll
      for (int j = 0; j < 4; j++) bv[j] = *(const bf16x8*)&Bs[bb + j * 128];
      #pragma unroll
      for (int i = 0; i < 4; i++)
        #pragma unroll
        for (int j = 0; j < 4; j++)
          acc[i][j] = __builtin_amdgcn_mfma_f32_16x16x32_bf16(av[i], bv[j], acc[i][j], 0, 0, 0);
    }
  }

  // ---- fused stats epilogue. C/D layout (m89, verified by R1 W-store):
  //      local row = i*16 + lg*4 + r, local col = j*16 + lr (within 64x64 quadrant).
  const int ebuf = tid >> 7;           // staging buffer (== wc of producer wave)
  const int erole = (tid >> 6) & 1;    // 0: col reduce, 1: row reduce
  const int l6 = tid & 63;
  float cAv[3] = {-3e38f,-3e38f,-3e38f}, cBv[3] = {-3e38f,-3e38f,-3e38f};
  int   cAi[3] = {-1,-1,-1},            cBi[3] = {-1,-1,-1};
  float cAs = 0.f, cAq = 0.f, cBs = 0.f, cBq = 0.f;

  for (int rnd = 0; rnd < 2; rnd++) {
    __syncthreads();                       // As/Bs (or prev round stg) dead
    if (wr == rnd) {
      float* st = stg + wc * 4160;
      #pragma unroll
      for (int i = 0; i < 4; i++)
        #pragma unroll
        for (int r = 0; r < 4; r++) {
          const int row = i * 16 + lg * 4 + r;
          #pragma unroll
          for (int j = 0; j < 4; j++)
            st[row * 65 + j * 16 + lr] = acc[i][j][r];
        }
    }
    __syncthreads();
    const float* st = stg + ebuf * 4160;
    if (erole == 0) {
      // column l6 of this quadrant; two independent 32-row chains, persist across rounds
      #pragma unroll 4
      for (int r = 0; r < 32; r++) {
        float wa = st[r * 65 + l6];
        float wb = st[(r + 32) * 65 + l6];
        cAs += wa; cAq += wa*wa; ins3(wa, rp*128 + rnd*64 + r,      cAv, cAi);
        cBs += wb; cBq += wb*wb; ins3(wb, rp*128 + rnd*64 + 32 + r, cBv, cBi);
      }
    } else {
      // row l6 of this quadrant; two independent 32-col chains, merged per round
      float rAv[3] = {-3e38f,-3e38f,-3e38f}, rBv[3] = {-3e38f,-3e38f,-3e38f};
      int   rAi[3] = {-1,-1,-1},            rBi[3] = {-1,-1,-1};
      float rAs = 0.f, rAq = 0.f, rBs = 0.f, rBq = 0.f;
      #pragma unroll 4
      for (int c = 0; c < 32; c++) {
        float wa = st[l6 * 65 + c];
        float wb = st[l6 * 65 + 32 + c];
        rAs += wa; rAq += wa*wa; ins3(wa, mp*128 + ebuf*64 + c,      rAv, rAi);
        rBs += wb; rBq += wb*wb; ins3(wb, mp*128 + ebuf*64 + 32 + c, rBv, rBi);
      }
      ins3(rBv[0], rBi[0], rAv, rAi);
      ins3(rBv[1], rBi[1], rAv, rAi);
      ins3(rBv[2], rBi[2], rAv, rAi);
      size_t rec = (((size_t)b*32 + mp*2 + ebuf)*LDIM + rp*128 + rnd*64 + l6) * 8;
      uint4 lo = make_uint4(__float_as_uint(rAv[0]), __float_as_uint(rAv[1]),
                            __float_as_uint(rAv[2]), __float_as_uint(rAs + rBs));
      uint4 hi = make_uint4(__float_as_uint(rAq + rBq), (unsigned)rAi[0],
                            (unsigned)rAi[1], (unsigned)rAi[2]);
      *(uint4*)(rowP + rec)     = lo;
      *(uint4*)(rowP + rec + 4) = hi;
    }
  }
  if (erole == 0) {
    ins3(cBv[0], cBi[0], cAv, cAi);
    ins3(cBv[1], cBi[1], cAv, cAi);
    ins3(cBv[2], cBi[2], cAv, cAi);
    size_t rec = (((size_t)b*16 + rp)*LDIM + mp*128 + ebuf*64 + l6) * 8;
    uint4 lo = make_uint4(__float_as_uint(cAv[0]), __float_as_uint(cAv[1]),
                          __float_as_uint(cAv[2]), __float_as_uint(cAs + cBs));
    uint4 hi = make_uint4(__float_as_uint(cAq + cBq), (unsigned)cAi[0],
                          (unsigned)cAi[1], (unsigned)cAi[2]);
    *(uint4*)(colP + rec)     = lo;
    *(uint4*)(colP + rec + 4) = hi;
  }
}

// Merge nt per-tile partials per index -> normalized top-3 weights + indices + std.
__global__ __launch_bounds__(256) void stats_combine(const unsigned* __restrict__ P,
    int nt, float* __restrict__ w3, int* __restrict__ i3, float* __restrict__ sd) {
  const int b = blockIdx.y;
  const int c = blockIdx.x * 256 + threadIdx.x;
  float v[3] = {-3e38f,-3e38f,-3e38f}; int id[3] = {-1,-1,-1};
  float sum = 0.f, sq = 0.f;
  for (int t = 0; t < nt; t++) {
    const unsigned* rec = P + (((size_t)b*nt + t)*LDIM + c) * 8;
    const uint4 lo = *(const uint4*)rec;
    const uint4 hi = *(const uint4*)(rec + 4);
    ins3(__uint_as_float(lo.x), (int)hi.y, v, id);
    ins3(__uint_as_float(lo.y), (int)hi.z, v, id);
    ins3(__uint_as_float(lo.z), (int)hi.w, v, id);
    sum += __uint_as_float(lo.w); sq += __uint_as_float(hi.x);
  }
  float inv = 1.f/(v[0]+v[1]+v[2]);
  size_t o = (size_t)b*LDIM + c;
  w3[o*3+0]=v[0]*inv; w3[o*3+1]=v[1]*inv; w3[o*3+2]=v[2]*inv;
  i3[o*3+0]=id[0]; i3[o*3+1]=id[1]; i3[o*3+2]=id[2];
  float mean = sum * (1.f/LDIM);
  float var = sq*(1.f/LDIM) - mean*mean;
  sd[o] = sqrtf(fmaxf(var, 0.f));
}

// att_merge_c[m][d] += wk_c[c][m] * ctx[c][d]  -- 3 targets per row c (scatter).
__global__ __launch_bounds__(128) void scatter_att(const float* __restrict__ ctx,
    const float* __restrict__ rw, const int* __restrict__ ri,
    float* __restrict__ attC) {
  const int b = blockIdx.y, c = blockIdx.x, d = threadIdx.x;
  const size_t base = (size_t)b*LDIM + c;
  const float x = ctx[base*DDIM + d];
  #pragma unroll
  for (int t = 0; t < 3; t++) {
    float w = rw[base*3 + t];
    int m = ri[base*3 + t];
    atomicAdd(&attC[((size_t)b*LDIM + m)*DDIM + d], w*x);
  }
}

// outputs_c = |ctx - gather(col top-3 of main)| * row_std   -> bf16
// outputs_m = |main - attC| * col_std                       -> bf16
// 4 rows/block, float2 per lane (8B loads), packed u32 stores.
__global__ __launch_bounds__(256) void make_outputs(const float* __restrict__ ctx,
    const float* __restrict__ mn, const float* __restrict__ attC,
    const float* __restrict__ rs, const float* __restrict__ cw,
    const int* __restrict__ ci, const float* __restrict__ cs,
    u16* __restrict__ outCb, u16* __restrict__ outMb) {
  const int b = blockIdx.y;
  const int i = blockIdx.x * 4 + (threadIdx.x >> 6);
  const int d2 = (threadIdx.x & 63) * 2;
  const size_t base = (size_t)b*LDIM + i;
  const float2 cx = *(const float2*)&ctx[base*DDIM + d2];
  const float2 mm = *(const float2*)&mn[base*DDIM + d2];
  const float2 ac = *(const float2*)&attC[base*DDIM + d2];
  float am0 = 0.f, am1 = 0.f;
  #pragma unroll
  for (int t = 0; t < 3; t++) {
    float w = cw[base*3 + t];
    const float2 g = *(const float2*)&mn[((size_t)b*LDIM + ci[base*3+t])*DDIM + d2];
    am0 += w * g.x; am1 += w * g.y;
  }
  const float rsv = rs[base], csv = cs[base];
  float oc0 = fabsf(cx.x - am0) * rsv, oc1 = fabsf(cx.y - am1) * rsv;
  float om0 = fabsf(mm.x - ac.x) * csv, om1 = fabsf(mm.y - ac.y) * csv;
  *(unsigned*)&outCb[base*DDIM + d2] = pk2(oc0, oc1);
  *(unsigned*)&outMb[base*DDIM + d2] = pk2(om0, om1);
}

// Convert conv weights to bf16 panel wB[ko 0..47][f 0..111][e 0..7]:
// wB[ko][f][e] = w[ks = ko/16][d = (ko%16)*8 + e][f], f >= FDIM -> 0.
__global__ __launch_bounds__(256) void conv_prep_w(const float* __restrict__ wv,
    u16* __restrict__ wB) {
  int idx = blockIdx.x * 256 + threadIdx.x;
  if (idx >= 48 * FPAD * 8) return;
  int e = idx & 7, f = (idx >> 3) % FPAD, ko = idx / (FPAD * 8);
  int ks = ko >> 4, d = ((ko & 15) << 3) | e;
  float val = (f < FDIM) ? wv[(ks * DDIM + d) * FDIM + f] : 0.f;
  wB[idx] = (u16)f2bfu(val);
}

// conv1d(KS=3) + bias + relu + maxpool as MFMA GEMM: y[t,f] = sum_k X[t+ks,d]*w[ks,d,f].
// Block: 256 thr = 4 waves, covers CT=64 t-rows x all 112 f. K=384 -> 12 MFMA/f-tile.
__global__ __launch_bounds__(256) void conv_mfma(const u16* __restrict__ XCb,
    const u16* __restrict__ XMb, const u16* __restrict__ wB,
    const float* __restrict__ bias, float* __restrict__ out) {
  const int b = blockIdx.y, z = blockIdx.z;
  const int t0 = blockIdx.x * CT;
  const u16* X = (z == 0 ? XCb : XMb) + (size_t)b * LDIM * DDIM;
  __shared__ u16 Xs[(CT + 2) * 128];   // rows of 256B, XOR-swizzled
  __shared__ float smax[FPAD];
  const int tid = threadIdx.x;
  for (int e = tid; e < (CT + 2) * 16; e += 256) {
    int row = e >> 4, c16 = e & 15;
    int t = t0 + row;
    uint4 val = (t < LDIM) ? *(const uint4*)&X[(size_t)t * DDIM + c16 * 8]
                           : make_uint4(0u, 0u, 0u, 0u);
    int byte = row * 256 + ((c16 * 16) ^ ((row & 7) << 4));
    *(uint4*)((char*)Xs + byte) = val;
  }
  if (tid < FPAD) smax[tid] = 0.f;
  __syncthreads();
  const int w = tid >> 6, lane = tid & 63;
  const int lr = lane & 15, lg = lane >> 4;
  const int lt0 = w * 16;
  bf16x8 av[12];
  #pragma unroll
  for (int kk = 0; kk < 12; kk++) {
    int ko = kk * 4 + lg;          // k-octet 0..47; k = ko*8+e
    int ks = ko >> 4, d8 = ko & 15;
    int row = lt0 + lr + ks;
    int byte = row * 256 + ((d8 * 16) ^ ((row & 7) << 4));
    av[kk] = *(const bf16x8*)((const char*)Xs + byte);
  }
  for (int ft = 0; ft < 7; ft++) {
    f32x4 acc = {0.f, 0.f, 0.f, 0.f};
    #pragma unroll
    for (int kk = 0; kk < 12; kk++) {
      int ko = kk * 4 + lg;
      bf16x8 bv = *(const bf16x8*)&wB[((size_t)ko * FPAD + ft * 16 + lr) * 8];
      acc = __builtin_amdgcn_mfma_f32_16x16x32_bf16(av[kk], bv, acc, 0, 0, 0);
    }
    int f = ft * 16 + lr;
    float bb = (f < FDIM) ? bias[f] : 0.f;
    float mx = 0.f;
    #pragma unroll
    for (int r = 0; r < 4; r++) {
      int t = t0 + lt0 + lg * 4 + r;
      float y = fmaxf(acc[r] + bb, 0.f);
      if (t <= LDIM - 3) mx = fmaxf(mx, y);   // invalid t -> 0 (safe: relu-max >= 0)
    }
    mx = fmaxf(mx, __shfl_xor(mx, 16));
    mx = fmaxf(mx, __shfl_xor(mx, 32));
    if (lg == 0 && f < FDIM)
      atomicMax((unsigned*)&smax[f], __float_as_uint(mx));
  }
  __syncthreads();
  if (tid < FDIM)
    atomicMax((unsigned*)&out[(size_t)b * (2 * FDIM) + z * FDIM + tid],
              __float_as_uint(smax[tid]));
}

extern "C" void kernel_launch(void* const* d_in, const int* in_sizes, int n_in,
                              void* d_out, int out_size, void* d_ws, size_t ws_size,
                              hipStream_t stream) {
  const float* ctx   = (const float*)d_in[0];
  const float* mn    = (const float*)d_in[1];
  const float* wconv = (const float*)d_in[2];
  const float* bias  = (const float*)d_in[3];
  float* out = (float*)d_out;

  // pool accumulators must start at 0 (d_out is poisoned before every call)
  hipMemsetAsync(d_out, 0, sizeof(float)*(size_t)out_size, stream);

  // Workspace: [wB bf16 weight panel: 64K floats reserved] then per-iteration arrays.
  const size_t wbFloats = 65536;
  // Per-batch (floats/dwords) -- W is never materialized:
  //   row partial records:  32*L*8     = 524288
  //   col partial records:  16*L*8     = 262144
  //   final stats:          14*L       = 28672
  //   attC:                 L*D        = 262144
  //   outCb+outMb (u16):    2*L*D u16  = 262144 float-equiv
  //   split-bf16 panels:    2*16*PANEL_U16/2 = 786432
  const size_t perBatchFloats = (size_t)32*LDIM*8 + (size_t)16*LDIM*8
                              + 14*(size_t)LDIM + (size_t)LDIM*DDIM + (size_t)LDIM*DDIM
                              + 2*(size_t)16*PANEL_U16/2;
  const size_t perBatchBytes = perBatchFloats * sizeof(float);
  int nbMax = (int)((ws_size - wbFloats*sizeof(float)) / perBatchBytes);
  if (nbMax < 1) nbMax = 1;
  if (nbMax > BDIM) nbMax = BDIM;

  u16* wB = (u16*)d_ws;
  float* iterBase = (float*)d_ws + wbFloats;
  conv_prep_w<<<dim3((48*FPAD*8 + 255)/256), 256, 0, stream>>>(wconv, wB);

  for (int b0 = 0; b0 < BDIM; b0 += nbMax) {
    const int nb = (BDIM - b0 < nbMax) ? (BDIM - b0) : nbMax;
    unsigned* rowP = (unsigned*)iterBase;
    unsigned* colP = rowP + (size_t)nb*32*LDIM*8;
    float* rowW = (float*)(colP + (size_t)nb*16*LDIM*8);
    int*   rowI = (int*)(rowW + (size_t)nb*LDIM*3);
    float* rowS = (float*)(rowI + (size_t)nb*LDIM*3);
    float* colW = rowS + (size_t)nb*LDIM;
    int*   colI = (int*)(colW + (size_t)nb*LDIM*3);
    float* colS = (float*)(colI + (size_t)nb*LDIM*3);
    float* attC = colS + (size_t)nb*LDIM;
    u16*   outCb = (u16*)(attC + (size_t)nb*LDIM*DDIM);
    u16*   outMb = outCb + (size_t)nb*LDIM*DDIM;
    u16*   ctxS = outMb + (size_t)nb*LDIM*DDIM;
    u16*   mnS  = ctxS + (size_t)nb*16*PANEL_U16;
    const float* ctxb = ctx + (size_t)b0*LDIM*DDIM;
    const float* mnb  = mn  + (size_t)b0*LDIM*DDIM;

    split_convert<<<dim3(128, nb), 256, 0, stream>>>(ctxb, mnb, ctxS, mnS);
    gemm_mfma<<<dim3(LDIM/128, LDIM/128, nb), 256, 0, stream>>>(
        ctxS, mnS, rowP, colP);
    stats_combine<<<dim3(LDIM/256, nb), 256, 0, stream>>>(rowP, 32, rowW, rowI, rowS);
    stats_combine<<<dim3(LDIM/256, nb), 256, 0, stream>>>(colP, 16, colW, colI, colS);
    hipMemsetAsync(attC, 0, (size_t)nb*LDIM*DDIM*sizeof(float), stream);
    scatter_att<<<dim3(LDIM, nb), 128, 0, stream>>>(ctxb, rowW, rowI, attC);
    make_outputs<<<dim3(LDIM/4, nb), 256, 0, stream>>>(ctxb, mnb, attC, rowS, colW, colI, colS, outCb, outMb);
    conv_mfma<<<dim3(LDIM/CT, nb, 2), 256, 0, stream>>>(
        outCb, outMb, wB, bias, out + (size_t)b0*2*FDIM);
  }
}

// Round 14
// 325.638 us; speedup vs baseline: 1.1101x; 1.1101x over previous
//
#include <hip/hip_runtime.h>
#include <math.h>

#define LDIM 2048
#define DDIM 128
#define BDIM 16
#define FDIM 100
// Split-K bf16 GEMM: A' = [AH | AL | AH], B' = [BH | BH | BL], K = 384.
// Panel layout per (batch,row-panel): [48 koct][128 row][8 elems] bf16 -> 16KB-contiguous K-tiles.
#define PANEL_U16 (48 * 1024)
// conv-as-GEMM: K = 3*128 = 384, N = 112 (100 filters padded to 7 tiles of 16)
#define FPAD 112
#define CT 64            // t-rows per conv block

typedef unsigned short u16;
typedef __bf16 bf16x8 __attribute__((ext_vector_type(8)));
typedef float f32x4 __attribute__((ext_vector_type(4)));

__device__ inline unsigned f2bfu(float x) {  // fp32 -> bf16 bits, RNE
  unsigned u = __float_as_uint(x);
  return (u + 0x7FFFu + ((u >> 16) & 1u)) >> 16;
}
__device__ inline unsigned pk2(float a, float b) {
  return f2bfu(a) | (f2bfu(b) << 16);
}
__device__ inline float bfhi(float x) {  // value of the bf16 hi part
  return __uint_as_float(f2bfu(x) << 16);
}

__device__ inline void glds16(const u16* g, u16* l) {
  __builtin_amdgcn_global_load_lds(
      (const __attribute__((address_space(1))) void*)g,
      (__attribute__((address_space(3))) void*)l, 16, 0, 0);
}

// Branchless top-3 insert: insert at slot 2, bubble via conditional swaps.
// ~15 flat VALU ops (3 cmp + cndmasks), no exec-mask juggling -- the branchy
// version's body ran nearly every wave-iteration anyway (P(any lane updates)
// ~= 1 for 64-lane waves). Strict '>' => identical selection on tie-free data.
__device__ inline void ins3(float w, int idx, float v[3], int id[3]) {
  bool c2 = w > v[2];
  v[2] = c2 ? w : v[2];   id[2] = c2 ? idx : id[2];
  bool c1 = v[2] > v[1];
  float t1 = v[1]; int u1 = id[1];
  v[1] = c1 ? v[2] : v[1]; id[1] = c1 ? id[2] : id[1];
  v[2] = c1 ? t1 : v[2];   id[2] = c1 ? u1 : id[2];
  bool c0 = v[1] > v[0];
  float t0 = v[0]; int u0 = id[0];
  v[0] = c0 ? v[1] : v[0]; id[0] = c0 ? id[1] : id[0];
  v[1] = c0 ? t0 : v[1];   id[1] = c0 ? u0 : id[1];
}

// Expand fp32 inputs into split-bf16 panel layout (hi/lo), both ctx and main.
__global__ __launch_bounds__(256) void split_convert(const float* __restrict__ ctx,
    const float* __restrict__ mn, u16* __restrict__ ctxS, u16* __restrict__ mnS) {
  const int b = blockIdx.y;
  const int rp = blockIdx.x & 15, og = blockIdx.x >> 4;  // og 0..7
  const int tid = threadIdx.x;
  const int row = tid & 127;
  const int o = og * 2 + (tid >> 7);                     // source k-octet 0..15
  const size_t srcOff = (((size_t)b * LDIM + rp * 128 + row) * DDIM + o * 8);
  const float4 c0 = *(const float4*)(ctx + srcOff);
  const float4 c1 = *(const float4*)(ctx + srcOff + 4);
  const float4 m0 = *(const float4*)(mn + srcOff);
  const float4 m1 = *(const float4*)(mn + srcOff + 4);
  uint4 chi = make_uint4(pk2(c0.x,c0.y), pk2(c0.z,c0.w), pk2(c1.x,c1.y), pk2(c1.z,c1.w));
  uint4 clo = make_uint4(pk2(c0.x-bfhi(c0.x), c0.y-bfhi(c0.y)),
                         pk2(c0.z-bfhi(c0.z), c0.w-bfhi(c0.w)),
                         pk2(c1.x-bfhi(c1.x), c1.y-bfhi(c1.y)),
                         pk2(c1.z-bfhi(c1.z), c1.w-bfhi(c1.w)));
  uint4 mhi = make_uint4(pk2(m0.x,m0.y), pk2(m0.z,m0.w), pk2(m1.x,m1.y), pk2(m1.z,m1.w));
  uint4 mlo = make_uint4(pk2(m0.x-bfhi(m0.x), m0.y-bfhi(m0.y)),
                         pk2(m0.z-bfhi(m0.z), m0.w-bfhi(m0.w)),
                         pk2(m1.x-bfhi(m1.x), m1.y-bfhi(m1.y)),
                         pk2(m1.z-bfhi(m1.z), m1.w-bfhi(m1.w)));
  u16* dA = ctxS + ((size_t)b * 16 + rp) * PANEL_U16;
  u16* dB = mnS  + ((size_t)b * 16 + rp) * PANEL_U16;
  const int base = o * 1024 + row * 8;
  *(uint4*)(dA + base)         = chi;   // koct o      : AH
  *(uint4*)(dA + base + 16384) = clo;   // koct o + 16 : AL
  *(uint4*)(dA + base + 32768) = chi;   // koct o + 32 : AH
  *(uint4*)(dB + base)         = mhi;   // koct o      : BH
  *(uint4*)(dB + base + 16384) = mhi;   // koct o + 16 : BH
  *(uint4*)(dB + base + 32768) = mlo;   // koct o + 32 : BL
}

// W[b][c][m] = ctx.main^T via split-bf16 MFMA (K=384). W is NEVER stored.
// Epilogue (R12-proven structure): each 64x64 wave-quadrant staged to a 64x65
// LDS buffer (overlaid on dead As/Bs; 2 buffers, 2 rounds), reduced by whole
// waves: wave0=cols/buf0, wave1=rows/buf0, wave2=cols/buf1, wave3=rows/buf1.
// Serial walks, no shuffles; partial records in R8 format.
__global__ __launch_bounds__(256) void gemm_mfma(const u16* __restrict__ A,
    const u16* __restrict__ B, unsigned* __restrict__ rowP,
    unsigned* __restrict__ colP) {
  __shared__ __attribute__((aligned(16))) char ldsbuf[33280];
  u16* As = (u16*)ldsbuf;            // 16 KB (main loop)
  u16* Bs = As + 8192;               // 16 KB (main loop)
  float* stg = (float*)ldsbuf;       // epilogue: 2 x 4160 floats (64x65 each)
  const int b = blockIdx.z;
  const int rp = blockIdx.y, mp = blockIdx.x;
  const int tid = threadIdx.x;
  const int w = tid >> 6, lane = tid & 63;
  const int lr = lane & 15, lg = lane >> 4;
  const int wr = w >> 1, wc = w & 1;
  const u16* srcA = A + ((size_t)b * 16 + rp) * PANEL_U16;
  const u16* srcB = B + ((size_t)b * 16 + mp) * PANEL_U16;
  f32x4 acc[4][4];
  const f32x4 zz = {0.f, 0.f, 0.f, 0.f};
  #pragma unroll
  for (int i = 0; i < 4; i++)
    #pragma unroll
    for (int j = 0; j < 4; j++) acc[i][j] = zz;

  for (int kt = 0; kt < 6; kt++) {
    if (kt) __syncthreads();
    const u16* sA = srcA + kt * 8192;
    const u16* sB = srcB + kt * 8192;
    #pragma unroll
    for (int q = 0; q < 4; q++) {
      const int c = q * 256 + w * 64;           // chunk index base for this wave
      glds16(sA + (size_t)(c + lane) * 8, As + c * 8);
      glds16(sB + (size_t)(c + lane) * 8, Bs + c * 8);
    }
    __syncthreads();
    #pragma unroll
    for (int ks = 0; ks < 2; ks++) {
      const int ab = (ks * 4 + lg) * 1024 + (wr * 64 + lr) * 8;
      const int bb = (ks * 4 + lg) * 1024 + (wc * 64 + lr) * 8;
      bf16x8 av[4], bv[4];
      #pragma unroll
      for (int i = 0; i < 4; i++) av[i] = *(const bf16x8*)&As[ab + i * 128];
      #pragma unroll
      for (int j = 0; j < 4; j++) bv[j] = *(const bf16x8*)&Bs[bb + j * 128];
      #pragma unroll
      for (int i = 0; i < 4; i++)
        #pragma unroll
        for (int j = 0; j < 4; j++)
          acc[i][j] = __builtin_amdgcn_mfma_f32_16x16x32_bf16(av[i], bv[j], acc[i][j], 0, 0, 0);
    }
  }

  // ---- fused stats epilogue. C/D layout (m89, verified by R1 W-store):
  //      local row = i*16 + lg*4 + r, local col = j*16 + lr (within 64x64 quadrant).
  for (int rnd = 0; rnd < 2; rnd++) {
    __syncthreads();                       // As/Bs (or prev round stg) dead
    if (wr == rnd) {
      float* st = stg + wc * 4160;
      #pragma unroll
      for (int i = 0; i < 4; i++)
        #pragma unroll
        for (int r = 0; r < 4; r++) {
          const int row = i * 16 + lg * 4 + r;
          #pragma unroll
          for (int j = 0; j < 4; j++)
            st[row * 65 + j * 16 + lr] = acc[i][j][r];
        }
    }
    __syncthreads();
    {
      const int buf = tid >> 7;            // which staging buffer (== wc)
      const int role = (tid >> 6) & 1;     // 0: col reduce, 1: row reduce
      const int l6 = tid & 63;
      const float* st = stg + buf * 4160;
      float v[3] = {-3e38f,-3e38f,-3e38f}; int id[3] = {-1,-1,-1};
      float sm = 0.f, s2 = 0.f;
      if (role == 0) {
        // column l6 of this quadrant, over its 64 rows
        #pragma unroll 8
        for (int r = 0; r < 64; r++) {
          float wv = st[r * 65 + l6];
          sm += wv; s2 += wv*wv; ins3(wv, rp*128 + rnd*64 + r, v, id);
        }
        size_t rec = (((size_t)b*32 + rp*2 + rnd)*LDIM + mp*128 + buf*64 + l6) * 8;
        uint4 lo = make_uint4(__float_as_uint(v[0]), __float_as_uint(v[1]),
                              __float_as_uint(v[2]), __float_as_uint(sm));
        uint4 hi = make_uint4(__float_as_uint(s2), (unsigned)id[0],
                              (unsigned)id[1], (unsigned)id[2]);
        *(uint4*)(colP + rec)     = lo;
        *(uint4*)(colP + rec + 4) = hi;
      } else {
        // row l6 of this quadrant, over its 64 cols
        #pragma unroll 8
        for (int c = 0; c < 64; c++) {
          float wv = st[l6 * 65 + c];
          sm += wv; s2 += wv*wv; ins3(wv, mp*128 + buf*64 + c, v, id);
        }
        size_t rec = (((size_t)b*32 + mp*2 + buf)*LDIM + rp*128 + rnd*64 + l6) * 8;
        uint4 lo = make_uint4(__float_as_uint(v[0]), __float_as_uint(v[1]),
                              __float_as_uint(v[2]), __float_as_uint(sm));
        uint4 hi = make_uint4(__float_as_uint(s2), (unsigned)id[0],
                              (unsigned)id[1], (unsigned)id[2]);
        *(uint4*)(rowP + rec)     = lo;
        *(uint4*)(rowP + rec + 4) = hi;
      }
    }
  }
}

// Merge nt per-tile partials per index -> normalized top-3 weights + indices + std.
__global__ __launch_bounds__(256) void stats_combine(const unsigned* __restrict__ P,
    int nt, float* __restrict__ w3, int* __restrict__ i3, float* __restrict__ sd) {
  const int b = blockIdx.y;
  const int c = blockIdx.x * 256 + threadIdx.x;
  float v[3] = {-3e38f,-3e38f,-3e38f}; int id[3] = {-1,-1,-1};
  float sum = 0.f, sq = 0.f;
  for (int t = 0; t < nt; t++) {
    const unsigned* rec = P + (((size_t)b*nt + t)*LDIM + c) * 8;
    const uint4 lo = *(const uint4*)rec;
    const uint4 hi = *(const uint4*)(rec + 4);
    ins3(__uint_as_float(lo.x), (int)hi.y, v, id);
    ins3(__uint_as_float(lo.y), (int)hi.z, v, id);
    ins3(__uint_as_float(lo.z), (int)hi.w, v, id);
    sum += __uint_as_float(lo.w); sq += __uint_as_float(hi.x);
  }
  float inv = 1.f/(v[0]+v[1]+v[2]);
  size_t o = (size_t)b*LDIM + c;
  w3[o*3+0]=v[0]*inv; w3[o*3+1]=v[1]*inv; w3[o*3+2]=v[2]*inv;
  i3[o*3+0]=id[0]; i3[o*3+1]=id[1]; i3[o*3+2]=id[2];
  float mean = sum * (1.f/LDIM);
  float var = sq*(1.f/LDIM) - mean*mean;
  sd[o] = sqrtf(fmaxf(var, 0.f));
}

// att_merge_c[m][d] += wk_c[c][m] * ctx[c][d]  -- 3 targets per row c (scatter).
__global__ __launch_bounds__(128) void scatter_att(const float* __restrict__ ctx,
    const float* __restrict__ rw, const int* __restrict__ ri,
    float* __restrict__ attC) {
  const int b = blockIdx.y, c = blockIdx.x, d = threadIdx.x;
  const size_t base = (size_t)b*LDIM + c;
  const float x = ctx[base*DDIM + d];
  #pragma unroll
  for (int t = 0; t < 3; t++) {
    float w = rw[base*3 + t];
    int m = ri[base*3 + t];
    atomicAdd(&attC[((size_t)b*LDIM + m)*DDIM + d], w*x);
  }
}

// outputs_c = |ctx - gather(col top-3 of main)| * row_std   -> bf16
// outputs_m = |main - attC| * col_std                       -> bf16
// 4 rows/block, float2 per lane (8B loads), packed u32 stores.
__global__ __launch_bounds__(256) void make_outputs(const float* __restrict__ ctx,
    const float* __restrict__ mn, const float* __restrict__ attC,
    const float* __restrict__ rs, const float* __restrict__ cw,
    const int* __restrict__ ci, const float* __restrict__ cs,
    u16* __restrict__ outCb, u16* __restrict__ outMb) {
  const int b = blockIdx.y;
  const int i = blockIdx.x * 4 + (threadIdx.x >> 6);
  const int d2 = (threadIdx.x & 63) * 2;
  const size_t base = (size_t)b*LDIM + i;
  const float2 cx = *(const float2*)&ctx[base*DDIM + d2];
  const float2 mm = *(const float2*)&mn[base*DDIM + d2];
  const float2 ac = *(const float2*)&attC[base*DDIM + d2];
  float am0 = 0.f, am1 = 0.f;
  #pragma unroll
  for (int t = 0; t < 3; t++) {
    float w = cw[base*3 + t];
    const float2 g = *(const float2*)&mn[((size_t)b*LDIM + ci[base*3+t])*DDIM + d2];
    am0 += w * g.x; am1 += w * g.y;
  }
  const float rsv = rs[base], csv = cs[base];
  float oc0 = fabsf(cx.x - am0) * rsv, oc1 = fabsf(cx.y - am1) * rsv;
  float om0 = fabsf(mm.x - ac.x) * csv, om1 = fabsf(mm.y - ac.y) * csv;
  *(unsigned*)&outCb[base*DDIM + d2] = pk2(oc0, oc1);
  *(unsigned*)&outMb[base*DDIM + d2] = pk2(om0, om1);
}

// Convert conv weights to bf16 panel wB[ko 0..47][f 0..111][e 0..7]:
// wB[ko][f][e] = w[ks = ko/16][d = (ko%16)*8 + e][f], f >= FDIM -> 0.
__global__ __launch_bounds__(256) void conv_prep_w(const float* __restrict__ wv,
    u16* __restrict__ wB) {
  int idx = blockIdx.x * 256 + threadIdx.x;
  if (idx >= 48 * FPAD * 8) return;
  int e = idx & 7, f = (idx >> 3) % FPAD, ko = idx / (FPAD * 8);
  int ks = ko >> 4, d = ((ko & 15) << 3) | e;
  float val = (f < FDIM) ? wv[(ks * DDIM + d) * FDIM + f] : 0.f;
  wB[idx] = (u16)f2bfu(val);
}

// conv1d(KS=3) + bias + relu + maxpool as MFMA GEMM: y[t,f] = sum_k X[t+ks,d]*w[ks,d,f].
// Block: 256 thr = 4 waves, covers CT=64 t-rows x all 112 f. K=384 -> 12 MFMA/f-tile.
__global__ __launch_bounds__(256) void conv_mfma(const u16* __restrict__ XCb,
    const u16* __restrict__ XMb, const u16* __restrict__ wB,
    const float* __restrict__ bias, float* __restrict__ out) {
  const int b = blockIdx.y, z = blockIdx.z;
  const int t0 = blockIdx.x * CT;
  const u16* X = (z == 0 ? XCb : XMb) + (size_t)b * LDIM * DDIM;
  __shared__ u16 Xs[(CT + 2) * 128];   // rows of 256B, XOR-swizzled
  __shared__ float smax[FPAD];
  const int tid = threadIdx.x;
  for (int e = tid; e < (CT + 2) * 16; e += 256) {
    int row = e >> 4, c16 = e & 15;
    int t = t0 + row;
    uint4 val = (t < LDIM) ? *(const uint4*)&X[(size_t)t * DDIM + c16 * 8]
                           : make_uint4(0u, 0u, 0u, 0u);
    int byte = row * 256 + ((c16 * 16) ^ ((row & 7) << 4));
    *(uint4*)((char*)Xs + byte) = val;
  }
  if (tid < FPAD) smax[tid] = 0.f;
  __syncthreads();
  const int w = tid >> 6, lane = tid & 63;
  const int lr = lane & 15, lg = lane >> 4;
  const int lt0 = w * 16;
  bf16x8 av[12];
  #pragma unroll
  for (int kk = 0; kk < 12; kk++) {
    int ko = kk * 4 + lg;          // k-octet 0..47; k = ko*8+e
    int ks = ko >> 4, d8 = ko & 15;
    int row = lt0 + lr + ks;
    int byte = row * 256 + ((d8 * 16) ^ ((row & 7) << 4));
    av[kk] = *(const bf16x8*)((const char*)Xs + byte);
  }
  for (int ft = 0; ft < 7; ft++) {
    f32x4 acc = {0.f, 0.f, 0.f, 0.f};
    #pragma unroll
    for (int kk = 0; kk < 12; kk++) {
      int ko = kk * 4 + lg;
      bf16x8 bv = *(const bf16x8*)&wB[((size_t)ko * FPAD + ft * 16 + lr) * 8];
      acc = __builtin_amdgcn_mfma_f32_16x16x32_bf16(av[kk], bv, acc, 0, 0, 0);
    }
    int f = ft * 16 + lr;
    float bb = (f < FDIM) ? bias[f] : 0.f;
    float mx = 0.f;
    #pragma unroll
    for (int r = 0; r < 4; r++) {
      int t = t0 + lt0 + lg * 4 + r;
      float y = fmaxf(acc[r] + bb, 0.f);
      if (t <= LDIM - 3) mx = fmaxf(mx, y);   // invalid t -> 0 (safe: relu-max >= 0)
    }
    mx = fmaxf(mx, __shfl_xor(mx, 16));
    mx = fmaxf(mx, __shfl_xor(mx, 32));
    if (lg == 0 && f < FDIM)
      atomicMax((unsigned*)&smax[f], __float_as_uint(mx));
  }
  __syncthreads();
  if (tid < FDIM)
    atomicMax((unsigned*)&out[(size_t)b * (2 * FDIM) + z * FDIM + tid],
              __float_as_uint(smax[tid]));
}

extern "C" void kernel_launch(void* const* d_in, const int* in_sizes, int n_in,
                              void* d_out, int out_size, void* d_ws, size_t ws_size,
                              hipStream_t stream) {
  const float* ctx   = (const float*)d_in[0];
  const float* mn    = (const float*)d_in[1];
  const float* wconv = (const float*)d_in[2];
  const float* bias  = (const float*)d_in[3];
  float* out = (float*)d_out;

  // pool accumulators must start at 0 (d_out is poisoned before every call)
  hipMemsetAsync(d_out, 0, sizeof(float)*(size_t)out_size, stream);

  // Workspace: [wB bf16 weight panel: 64K floats reserved] then per-iteration arrays.
  const size_t wbFloats = 65536;
  // Per-batch (floats/dwords) -- W is never materialized:
  //   row partial records:  32*L*8     = 524288
  //   col partial records:  32*L*8     = 524288
  //   final stats:          14*L       = 28672
  //   attC:                 L*D        = 262144
  //   outCb+outMb (u16):    2*L*D u16  = 262144 float-equiv
  //   split-bf16 panels:    2*16*PANEL_U16/2 = 786432
  const size_t perBatchFloats = (size_t)32*LDIM*8 + (size_t)32*LDIM*8
                              + 14*(size_t)LDIM + (size_t)LDIM*DDIM + (size_t)LDIM*DDIM
                              + 2*(size_t)16*PANEL_U16/2;
  const size_t perBatchBytes = perBatchFloats * sizeof(float);
  int nbMax = (int)((ws_size - wbFloats*sizeof(float)) / perBatchBytes);
  if (nbMax < 1) nbMax = 1;
  if (nbMax > BDIM) nbMax = BDIM;

  u16* wB = (u16*)d_ws;
  float* iterBase = (float*)d_ws + wbFloats;
  conv_prep_w<<<dim3((48*FPAD*8 + 255)/256), 256, 0, stream>>>(wconv, wB);

  for (int b0 = 0; b0 < BDIM; b0 += nbMax) {
    const int nb = (BDIM - b0 < nbMax) ? (BDIM - b0) : nbMax;
    unsigned* rowP = (unsigned*)iterBase;
    unsigned* colP = rowP + (size_t)nb*32*LDIM*8;
    float* rowW = (float*)(colP + (size_t)nb*32*LDIM*8);
    int*   rowI = (int*)(rowW + (size_t)nb*LDIM*3);
    float* rowS = (float*)(rowI + (size_t)nb*LDIM*3);
    float* colW = rowS + (size_t)nb*LDIM;
    int*   colI = (int*)(colW + (size_t)nb*LDIM*3);
    float* colS = (float*)(colI + (size_t)nb*LDIM*3);
    float* attC = colS + (size_t)nb*LDIM;
    u16*   outCb = (u16*)(attC + (size_t)nb*LDIM*DDIM);
    u16*   outMb = outCb + (size_t)nb*LDIM*DDIM;
    u16*   ctxS = outMb + (size_t)nb*LDIM*DDIM;
    u16*   mnS  = ctxS + (size_t)nb*16*PANEL_U16;
    const float* ctxb = ctx + (size_t)b0*LDIM*DDIM;
    const float* mnb  = mn  + (size_t)b0*LDIM*DDIM;

    split_convert<<<dim3(128, nb), 256, 0, stream>>>(ctxb, mnb, ctxS, mnS);
    gemm_mfma<<<dim3(LDIM/128, LDIM/128, nb), 256, 0, stream>>>(
        ctxS, mnS, rowP, colP);
    stats_combine<<<dim3(LDIM/256, nb), 256, 0, stream>>>(rowP, 32, rowW, rowI, rowS);
    stats_combine<<<dim3(LDIM/256, nb), 256, 0, stream>>>(colP, 32, colW, colI, colS);
    hipMemsetAsync(attC, 0, (size_t)nb*LDIM*DDIM*sizeof(float), stream);
    scatter_att<<<dim3(LDIM, nb), 128, 0, stream>>>(ctxb, rowW, rowI, attC);
    make_outputs<<<dim3(LDIM/4, nb), 256, 0, stream>>>(ctxb, mnb, attC, rowS, colW, colI, colS, outCb, outMb);
    conv_mfma<<<dim3(LDIM/CT, nb, 2), 256, 0, stream>>>(
        outCb, outMb, wB, bias, out + (size_t)b0*2*FDIM);
  }
}

// Round 16
// 311.174 us; speedup vs baseline: 1.1617x; 1.0465x over previous
//
#include <hip/hip_runtime.h>
#include <math.h>

#define LDIM 2048
#define DDIM 128
#define BDIM 16
#define FDIM 100
// Split-K bf16 GEMM: A' = [AH | AL | AH], B' = [BH | BH | BL], K = 384.
// Panel layout per (batch,row-panel): [48 koct][128 row][8 elems] bf16 -> 16KB-contiguous K-tiles.
#define PANEL_U16 (48 * 1024)
// conv-as-GEMM: K = 3*128 = 384, N = 112 (100 filters padded to 7 tiles of 16)
#define FPAD 112
#define CT 64            // t-rows per conv block

typedef unsigned short u16;
typedef __bf16 bf16x8 __attribute__((ext_vector_type(8)));
typedef float f32x4 __attribute__((ext_vector_type(4)));

__device__ inline unsigned f2bfu(float x) {  // fp32 -> bf16 bits, RNE
  unsigned u = __float_as_uint(x);
  return (u + 0x7FFFu + ((u >> 16) & 1u)) >> 16;
}
__device__ inline unsigned pk2(float a, float b) {
  return f2bfu(a) | (f2bfu(b) << 16);
}
__device__ inline float bfhi(float x) {  // value of the bf16 hi part
  return __uint_as_float(f2bfu(x) << 16);
}

__device__ inline void glds16(const u16* g, u16* l) {
  __builtin_amdgcn_global_load_lds(
      (const __attribute__((address_space(1))) void*)g,
      (__attribute__((address_space(3))) void*)l, 16, 0, 0);
}

// Exact top-3 insert, med3-accelerated. Values (4 ops, exact fp32):
//   v0' = max(v0,w); v1' = med3(v0,v1,w); v2' = max(v2, min(v1,w))
// Indices: 3 exact fp32 compares + 5 selects. NO value approximation --
// R10/R15 proved index selection needs full fp32 resolution of W.
__device__ inline void ins3(float w, int idx, float v[3], int id[3]) {
  bool c0 = w > v[0], c1 = w > v[1], c2 = w > v[2];
  int n0 = c0 ? idx : id[0];
  int n1 = c0 ? id[0] : (c1 ? idx : id[1]);
  int n2 = c1 ? id[1] : (c2 ? idx : id[2]);
  id[0] = n0; id[1] = n1; id[2] = n2;
  float nv2 = fmaxf(v[2], fminf(v[1], w));       // min3(v0,v1,w) == min(v1,w) since v1<=v0
  float nv1 = __builtin_amdgcn_fmed3f(v[0], v[1], w);
  v[0] = fmaxf(v[0], w);
  v[1] = nv1; v[2] = nv2;
}

// Expand fp32 inputs into split-bf16 panel layout (hi/lo), both ctx and main.
__global__ __launch_bounds__(256) void split_convert(const float* __restrict__ ctx,
    const float* __restrict__ mn, u16* __restrict__ ctxS, u16* __restrict__ mnS) {
  const int b = blockIdx.y;
  const int rp = blockIdx.x & 15, og = blockIdx.x >> 4;  // og 0..7
  const int tid = threadIdx.x;
  const int row = tid & 127;
  const int o = og * 2 + (tid >> 7);                     // source k-octet 0..15
  const size_t srcOff = (((size_t)b * LDIM + rp * 128 + row) * DDIM + o * 8);
  const float4 c0 = *(const float4*)(ctx + srcOff);
  const float4 c1 = *(const float4*)(ctx + srcOff + 4);
  const float4 m0 = *(const float4*)(mn + srcOff);
  const float4 m1 = *(const float4*)(mn + srcOff + 4);
  uint4 chi = make_uint4(pk2(c0.x,c0.y), pk2(c0.z,c0.w), pk2(c1.x,c1.y), pk2(c1.z,c1.w));
  uint4 clo = make_uint4(pk2(c0.x-bfhi(c0.x), c0.y-bfhi(c0.y)),
                         pk2(c0.z-bfhi(c0.z), c0.w-bfhi(c0.w)),
                         pk2(c1.x-bfhi(c1.x), c1.y-bfhi(c1.y)),
                         pk2(c1.z-bfhi(c1.z), c1.w-bfhi(c1.w)));
  uint4 mhi = make_uint4(pk2(m0.x,m0.y), pk2(m0.z,m0.w), pk2(m1.x,m1.y), pk2(m1.z,m1.w));
  uint4 mlo = make_uint4(pk2(m0.x-bfhi(m0.x), m0.y-bfhi(m0.y)),
                         pk2(m0.z-bfhi(m0.z), m0.w-bfhi(m0.w)),
                         pk2(m1.x-bfhi(m1.x), m1.y-bfhi(m1.y)),
                         pk2(m1.z-bfhi(m1.z), m1.w-bfhi(m1.w)));
  u16* dA = ctxS + ((size_t)b * 16 + rp) * PANEL_U16;
  u16* dB = mnS  + ((size_t)b * 16 + rp) * PANEL_U16;
  const int base = o * 1024 + row * 8;
  *(uint4*)(dA + base)         = chi;   // koct o      : AH
  *(uint4*)(dA + base + 16384) = clo;   // koct o + 16 : AL
  *(uint4*)(dA + base + 32768) = chi;   // koct o + 32 : AH
  *(uint4*)(dB + base)         = mhi;   // koct o      : BH
  *(uint4*)(dB + base + 16384) = mhi;   // koct o + 16 : BH
  *(uint4*)(dB + base + 32768) = mlo;   // koct o + 32 : BL
}

// W[b][c][m] = ctx.main^T via split-bf16 MFMA (K=384). W is NEVER stored.
// Epilogue (R12-proven structure): each 64x64 wave-quadrant staged to a 64x65
// LDS buffer (overlaid on dead As/Bs; 2 buffers, 2 rounds), reduced by whole
// waves: wave0=cols/buf0, wave1=rows/buf0, wave2=cols/buf1, wave3=rows/buf1.
// Serial walks, no shuffles; partial records in R8 format.
__global__ __launch_bounds__(256) void gemm_mfma(const u16* __restrict__ A,
    const u16* __restrict__ B, unsigned* __restrict__ rowP,
    unsigned* __restrict__ colP) {
  __shared__ __attribute__((aligned(16))) char ldsbuf[33280];
  u16* As = (u16*)ldsbuf;            // 16 KB (main loop)
  u16* Bs = As + 8192;               // 16 KB (main loop)
  float* stg = (float*)ldsbuf;       // epilogue: 2 x 4160 floats (64x65 each)
  const int b = blockIdx.z;
  const int rp = blockIdx.y, mp = blockIdx.x;
  const int tid = threadIdx.x;
  const int w = tid >> 6, lane = tid & 63;
  const int lr = lane & 15, lg = lane >> 4;
  const int wr = w >> 1, wc = w & 1;
  const u16* srcA = A + ((size_t)b * 16 + rp) * PANEL_U16;
  const u16* srcB = B + ((size_t)b * 16 + mp) * PANEL_U16;
  f32x4 acc[4][4];
  const f32x4 zz = {0.f, 0.f, 0.f, 0.f};
  #pragma unroll
  for (int i = 0; i < 4; i++)
    #pragma unroll
    for (int j = 0; j < 4; j++) acc[i][j] = zz;

  for (int kt = 0; kt < 6; kt++) {
    if (kt) __syncthreads();
    const u16* sA = srcA + kt * 8192;
    const u16* sB = srcB + kt * 8192;
    #pragma unroll
    for (int q = 0; q < 4; q++) {
      const int c = q * 256 + w * 64;           // chunk index base for this wave
      glds16(sA + (size_t)(c + lane) * 8, As + c * 8);
      glds16(sB + (size_t)(c + lane) * 8, Bs + c * 8);
    }
    __syncthreads();
    #pragma unroll
    for (int ks = 0; ks < 2; ks++) {
      const int ab = (ks * 4 + lg) * 1024 + (wr * 64 + lr) * 8;
      const int bb = (ks * 4 + lg) * 1024 + (wc * 64 + lr) * 8;
      bf16x8 av[4], bv[4];
      #pragma unroll
      for (int i = 0; i < 4; i++) av[i] = *(const bf16x8*)&As[ab + i * 128];
      #pragma unroll
      for (int j = 0; j < 4; j++) bv[j] = *(const bf16x8*)&Bs[bb + j * 128];
      #pragma unroll
      for (int i = 0; i < 4; i++)
        #pragma unroll
        for (int j = 0; j < 4; j++)
          acc[i][j] = __builtin_amdgcn_mfma_f32_16x16x32_bf16(av[i], bv[j], acc[i][j], 0, 0, 0);
    }
  }

  // ---- fused stats epilogue. C/D layout (m89, verified by R1 W-store):
  //      local row = i*16 + lg*4 + r, local col = j*16 + lr (within 64x64 quadrant).
  for (int rnd = 0; rnd < 2; rnd++) {
    __syncthreads();                       // As/Bs (or prev round stg) dead
    if (wr == rnd) {
      float* st = stg + wc * 4160;
      #pragma unroll
      for (int i = 0; i < 4; i++)
        #pragma unroll
        for (int r = 0; r < 4; r++) {
          const int row = i * 16 + lg * 4 + r;
          #pragma unroll
          for (int j = 0; j < 4; j++)
            st[row * 65 + j * 16 + lr] = acc[i][j][r];
        }
    }
    __syncthreads();
    {
      const int buf = tid >> 7;            // which staging buffer (== wc)
      const int role = (tid >> 6) & 1;     // 0: col reduce, 1: row reduce
      const int l6 = tid & 63;
      const float* st = stg + buf * 4160;
      float v[3] = {-3e38f,-3e38f,-3e38f}; int id[3] = {-1,-1,-1};
      float sm = 0.f, s2 = 0.f;
      if (role == 0) {
        // column l6 of this quadrant, over its 64 rows
        #pragma unroll 8
        for (int r = 0; r < 64; r++) {
          float wv = st[r * 65 + l6];
          sm += wv; s2 = fmaf(wv, wv, s2);
          ins3(wv, rp*128 + rnd*64 + r, v, id);
        }
        size_t rec = (((size_t)b*32 + rp*2 + rnd)*LDIM + mp*128 + buf*64 + l6) * 8;
        uint4 lo = make_uint4(__float_as_uint(v[0]), __float_as_uint(v[1]),
                              __float_as_uint(v[2]), __float_as_uint(sm));
        uint4 hi = make_uint4(__float_as_uint(s2), (unsigned)id[0],
                              (unsigned)id[1], (unsigned)id[2]);
        *(uint4*)(colP + rec)     = lo;
        *(uint4*)(colP + rec + 4) = hi;
      } else {
        // row l6 of this quadrant, over its 64 cols
        #pragma unroll 8
        for (int c = 0; c < 64; c++) {
          float wv = st[l6 * 65 + c];
          sm += wv; s2 = fmaf(wv, wv, s2);
          ins3(wv, mp*128 + buf*64 + c, v, id);
        }
        size_t rec = (((size_t)b*32 + mp*2 + buf)*LDIM + rp*128 + rnd*64 + l6) * 8;
        uint4 lo = make_uint4(__float_as_uint(v[0]), __float_as_uint(v[1]),
                              __float_as_uint(v[2]), __float_as_uint(sm));
        uint4 hi = make_uint4(__float_as_uint(s2), (unsigned)id[0],
                              (unsigned)id[1], (unsigned)id[2]);
        *(uint4*)(rowP + rec)     = lo;
        *(uint4*)(rowP + rec + 4) = hi;
      }
    }
  }
}

// Merge nt per-tile partials per index -> normalized top-3 weights + indices + std.
__global__ __launch_bounds__(256) void stats_combine(const unsigned* __restrict__ P,
    int nt, float* __restrict__ w3, int* __restrict__ i3, float* __restrict__ sd) {
  const int b = blockIdx.y;
  const int c = blockIdx.x * 256 + threadIdx.x;
  float v[3] = {-3e38f,-3e38f,-3e38f}; int id[3] = {-1,-1,-1};
  float sum = 0.f, sq = 0.f;
  for (int t = 0; t < nt; t++) {
    const unsigned* rec = P + (((size_t)b*nt + t)*LDIM + c) * 8;
    const uint4 lo = *(const uint4*)rec;
    const uint4 hi = *(const uint4*)(rec + 4);
    ins3(__uint_as_float(lo.x), (int)hi.y, v, id);
    ins3(__uint_as_float(lo.y), (int)hi.z, v, id);
    ins3(__uint_as_float(lo.z), (int)hi.w, v, id);
    sum += __uint_as_float(lo.w); sq += __uint_as_float(hi.x);
  }
  float inv = 1.f/(v[0]+v[1]+v[2]);
  size_t o = (size_t)b*LDIM + c;
  w3[o*3+0]=v[0]*inv; w3[o*3+1]=v[1]*inv; w3[o*3+2]=v[2]*inv;
  i3[o*3+0]=id[0]; i3[o*3+1]=id[1]; i3[o*3+2]=id[2];
  float mean = sum * (1.f/LDIM);
  float var = sq*(1.f/LDIM) - mean*mean;
  sd[o] = sqrtf(fmaxf(var, 0.f));
}

// att_merge_c[m][d] += wk_c[c][m] * ctx[c][d]  -- 3 targets per row c (scatter).
__global__ __launch_bounds__(128) void scatter_att(const float* __restrict__ ctx,
    const float* __restrict__ rw, const int* __restrict__ ri,
    float* __restrict__ attC) {
  const int b = blockIdx.y, c = blockIdx.x, d = threadIdx.x;
  const size_t base = (size_t)b*LDIM + c;
  const float x = ctx[base*DDIM + d];
  #pragma unroll
  for (int t = 0; t < 3; t++) {
    float w = rw[base*3 + t];
    int m = ri[base*3 + t];
    atomicAdd(&attC[((size_t)b*LDIM + m)*DDIM + d], w*x);
  }
}

// outputs_c = |ctx - gather(col top-3 of main)| * row_std   -> bf16
// outputs_m = |main - attC| * col_std                       -> bf16
// 4 rows/block, float2 per lane (8B loads), packed u32 stores.
__global__ __launch_bounds__(256) void make_outputs(const float* __restrict__ ctx,
    const float* __restrict__ mn, const float* __restrict__ attC,
    const float* __restrict__ rs, const float* __restrict__ cw,
    const int* __restrict__ ci, const float* __restrict__ cs,
    u16* __restrict__ outCb, u16* __restrict__ outMb) {
  const int b = blockIdx.y;
  const int i = blockIdx.x * 4 + (threadIdx.x >> 6);
  const int d2 = (threadIdx.x & 63) * 2;
  const size_t base = (size_t)b*LDIM + i;
  const float2 cx = *(const float2*)&ctx[base*DDIM + d2];
  const float2 mm = *(const float2*)&mn[base*DDIM + d2];
  const float2 ac = *(const float2*)&attC[base*DDIM + d2];
  float am0 = 0.f, am1 = 0.f;
  #pragma unroll
  for (int t = 0; t < 3; t++) {
    float w = cw[base*3 + t];
    const float2 g = *(const float2*)&mn[((size_t)b*LDIM + ci[base*3+t])*DDIM + d2];
    am0 += w * g.x; am1 += w * g.y;
  }
  const float rsv = rs[base], csv = cs[base];
  float oc0 = fabsf(cx.x - am0) * rsv, oc1 = fabsf(cx.y - am1) * rsv;
  float om0 = fabsf(mm.x - ac.x) * csv, om1 = fabsf(mm.y - ac.y) * csv;
  *(unsigned*)&outCb[base*DDIM + d2] = pk2(oc0, oc1);
  *(unsigned*)&outMb[base*DDIM + d2] = pk2(om0, om1);
}

// Convert conv weights to bf16 panel wB[ko 0..47][f 0..111][e 0..7]:
// wB[ko][f][e] = w[ks = ko/16][d = (ko%16)*8 + e][f], f >= FDIM -> 0.
__global__ __launch_bounds__(256) void conv_prep_w(const float* __restrict__ wv,
    u16* __restrict__ wB) {
  int idx = blockIdx.x * 256 + threadIdx.x;
  if (idx >= 48 * FPAD * 8) return;
  int e = idx & 7, f = (idx >> 3) % FPAD, ko = idx / (FPAD * 8);
  int ks = ko >> 4, d = ((ko & 15) << 3) | e;
  float val = (f < FDIM) ? wv[(ks * DDIM + d) * FDIM + f] : 0.f;
  wB[idx] = (u16)f2bfu(val);
}

// conv1d(KS=3) + bias + relu + maxpool as MFMA GEMM: y[t,f] = sum_k X[t+ks,d]*w[ks,d,f].
// Block: 256 thr = 4 waves, covers CT=64 t-rows x all 112 f. K=384 -> 12 MFMA/f-tile.
__global__ __launch_bounds__(256) void conv_mfma(const u16* __restrict__ XCb,
    const u16* __restrict__ XMb, const u16* __restrict__ wB,
    const float* __restrict__ bias, float* __restrict__ out) {
  const int b = blockIdx.y, z = blockIdx.z;
  const int t0 = blockIdx.x * CT;
  const u16* X = (z == 0 ? XCb : XMb) + (size_t)b * LDIM * DDIM;
  __shared__ u16 Xs[(CT + 2) * 128];   // rows of 256B, XOR-swizzled
  __shared__ float smax[FPAD];
  const int tid = threadIdx.x;
  for (int e = tid; e < (CT + 2) * 16; e += 256) {
    int row = e >> 4, c16 = e & 15;
    int t = t0 + row;
    uint4 val = (t < LDIM) ? *(const uint4*)&X[(size_t)t * DDIM + c16 * 8]
                           : make_uint4(0u, 0u, 0u, 0u);
    int byte = row * 256 + ((c16 * 16) ^ ((row & 7) << 4));
    *(uint4*)((char*)Xs + byte) = val;
  }
  if (tid < FPAD) smax[tid] = 0.f;
  __syncthreads();
  const int w = tid >> 6, lane = tid & 63;
  const int lr = lane & 15, lg = lane >> 4;
  const int lt0 = w * 16;
  bf16x8 av[12];
  #pragma unroll
  for (int kk = 0; kk < 12; kk++) {
    int ko = kk * 4 + lg;          // k-octet 0..47; k = ko*8+e
    int ks = ko >> 4, d8 = ko & 15;
    int row = lt0 + lr + ks;
    int byte = row * 256 + ((d8 * 16) ^ ((row & 7) << 4));
    av[kk] = *(const bf16x8*)((const char*)Xs + byte);
  }
  for (int ft = 0; ft < 7; ft++) {
    f32x4 acc = {0.f, 0.f, 0.f, 0.f};
    #pragma unroll
    for (int kk = 0; kk < 12; kk++) {
      int ko = kk * 4 + lg;
      bf16x8 bv = *(const bf16x8*)&wB[((size_t)ko * FPAD + ft * 16 + lr) * 8];
      acc = __builtin_amdgcn_mfma_f32_16x16x32_bf16(av[kk], bv, acc, 0, 0, 0);
    }
    int f = ft * 16 + lr;
    float bb = (f < FDIM) ? bias[f] : 0.f;
    float mx = 0.f;
    #pragma unroll
    for (int r = 0; r < 4; r++) {
      int t = t0 + lt0 + lg * 4 + r;
      float y = fmaxf(acc[r] + bb, 0.f);
      if (t <= LDIM - 3) mx = fmaxf(mx, y);   // invalid t -> 0 (safe: relu-max >= 0)
    }
    mx = fmaxf(mx, __shfl_xor(mx, 16));
    mx = fmaxf(mx, __shfl_xor(mx, 32));
    if (lg == 0 && f < FDIM)
      atomicMax((unsigned*)&smax[f], __float_as_uint(mx));
  }
  __syncthreads();
  if (tid < FDIM)
    atomicMax((unsigned*)&out[(size_t)b * (2 * FDIM) + z * FDIM + tid],
              __float_as_uint(smax[tid]));
}

extern "C" void kernel_launch(void* const* d_in, const int* in_sizes, int n_in,
                              void* d_out, int out_size, void* d_ws, size_t ws_size,
                              hipStream_t stream) {
  const float* ctx   = (const float*)d_in[0];
  const float* mn    = (const float*)d_in[1];
  const float* wconv = (const float*)d_in[2];
  const float* bias  = (const float*)d_in[3];
  float* out = (float*)d_out;

  // pool accumulators must start at 0 (d_out is poisoned before every call)
  hipMemsetAsync(d_out, 0, sizeof(float)*(size_t)out_size, stream);

  // Workspace: [wB bf16 weight panel: 64K floats reserved] then per-iteration arrays.
  const size_t wbFloats = 65536;
  // Per-batch (floats/dwords) -- W is never materialized:
  //   row partial records:  32*L*8     = 524288
  //   col partial records:  32*L*8     = 524288
  //   final stats:          14*L       = 28672
  //   attC:                 L*D        = 262144
  //   outCb+outMb (u16):    2*L*D u16  = 262144 float-equiv
  //   split-bf16 panels:    2*16*PANEL_U16/2 = 786432
  const size_t perBatchFloats = (size_t)32*LDIM*8 + (size_t)32*LDIM*8
                              + 14*(size_t)LDIM + (size_t)LDIM*DDIM + (size_t)LDIM*DDIM
                              + 2*(size_t)16*PANEL_U16/2;
  const size_t perBatchBytes = perBatchFloats * sizeof(float);
  int nbMax = (int)((ws_size - wbFloats*sizeof(float)) / perBatchBytes);
  if (nbMax < 1) nbMax = 1;
  if (nbMax > BDIM) nbMax = BDIM;

  u16* wB = (u16*)d_ws;
  float* iterBase = (float*)d_ws + wbFloats;
  conv_prep_w<<<dim3((48*FPAD*8 + 255)/256), 256, 0, stream>>>(wconv, wB);

  for (int b0 = 0; b0 < BDIM; b0 += nbMax) {
    const int nb = (BDIM - b0 < nbMax) ? (BDIM - b0) : nbMax;
    unsigned* rowP = (unsigned*)iterBase;
    unsigned* colP = rowP + (size_t)nb*32*LDIM*8;
    float* rowW = (float*)(colP + (size_t)nb*32*LDIM*8);
    int*   rowI = (int*)(rowW + (size_t)nb*LDIM*3);
    float* rowS = (float*)(rowI + (size_t)nb*LDIM*3);
    float* colW = rowS + (size_t)nb*LDIM;
    int*   colI = (int*)(colW + (size_t)nb*LDIM*3);
    float* colS = (float*)(colI + (size_t)nb*LDIM*3);
    float* attC = colS + (size_t)nb*LDIM;
    u16*   outCb = (u16*)(attC + (size_t)nb*LDIM*DDIM);
    u16*   outMb = outCb + (size_t)nb*LDIM*DDIM;
    u16*   ctxS = outMb + (size_t)nb*LDIM*DDIM;
    u16*   mnS  = ctxS + (size_t)nb*16*PANEL_U16;
    const float* ctxb = ctx + (size_t)b0*LDIM*DDIM;
    const float* mnb  = mn  + (size_t)b0*LDIM*DDIM;

    split_convert<<<dim3(128, nb), 256, 0, stream>>>(ctxb, mnb, ctxS, mnS);
    gemm_mfma<<<dim3(LDIM/128, LDIM/128, nb), 256, 0, stream>>>(
        ctxS, mnS, rowP, colP);
    stats_combine<<<dim3(LDIM/256, nb), 256, 0, stream>>>(rowP, 32, rowW, rowI, rowS);
    stats_combine<<<dim3(LDIM/256, nb), 256, 0, stream>>>(colP, 32, colW, colI, colS);
    hipMemsetAsync(attC, 0, (size_t)nb*LDIM*DDIM*sizeof(float), stream);
    scatter_att<<<dim3(LDIM, nb), 128, 0, stream>>>(ctxb, rowW, rowI, attC);
    make_outputs<<<dim3(LDIM/4, nb), 256, 0, stream>>>(ctxb, mnb, attC, rowS, colW, colI, colS, outCb, outMb);
    conv_mfma<<<dim3(LDIM/CT, nb, 2), 256, 0, stream>>>(
        outCb, outMb, wB, bias, out + (size_t)b0*2*FDIM);
  }
}

// Round 17
// 291.337 us; speedup vs baseline: 1.2408x; 1.0681x over previous
//
#include <hip/hip_runtime.h>
#include <math.h>

#define LDIM 2048
#define DDIM 128
#define BDIM 16
#define FDIM 100
// Split-K bf16 GEMM, dedup'd panels: A' = [AH | AL], B' = [BH | BL] (K=256 stored).
// Per 32-K chunk the 3 Markidis products are computed explicitly:
//   acc += AH.BH + AL.BH + AH.BL   (== fp32 ctx.main^T to ~1e-4)
// Panel layout per (batch,row-panel): [32 koct][128 row][8 elems] bf16.
#define PANEL_U16 (32 * 1024)
// conv-as-GEMM: K = 3*128 = 384, N = 112 (100 filters padded to 7 tiles of 16)
#define FPAD 112
#define CT 64            // t-rows per conv block

typedef unsigned short u16;
typedef __bf16 bf16x8 __attribute__((ext_vector_type(8)));
typedef float f32x4 __attribute__((ext_vector_type(4)));

__device__ inline unsigned f2bfu(float x) {  // fp32 -> bf16 bits, RNE
  unsigned u = __float_as_uint(x);
  return (u + 0x7FFFu + ((u >> 16) & 1u)) >> 16;
}
__device__ inline unsigned pk2(float a, float b) {
  return f2bfu(a) | (f2bfu(b) << 16);
}
__device__ inline float bfhi(float x) {  // value of the bf16 hi part
  return __uint_as_float(f2bfu(x) << 16);
}

__device__ inline void glds16(const u16* g, u16* l) {
  __builtin_amdgcn_global_load_lds(
      (const __attribute__((address_space(1))) void*)g,
      (__attribute__((address_space(3))) void*)l, 16, 0, 0);
}

// Exact top-3 insert, med3-accelerated. Values (4 ops, exact fp32):
//   v0' = max(v0,w); v1' = med3(v0,v1,w); v2' = max(v2, min(v1,w))
// Indices: 3 exact fp32 compares + 5 selects. NO value approximation --
// R10/R15 proved index selection needs full fp32 resolution of W.
__device__ inline void ins3(float w, int idx, float v[3], int id[3]) {
  bool c0 = w > v[0], c1 = w > v[1], c2 = w > v[2];
  int n0 = c0 ? idx : id[0];
  int n1 = c0 ? id[0] : (c1 ? idx : id[1]);
  int n2 = c1 ? id[1] : (c2 ? idx : id[2]);
  id[0] = n0; id[1] = n1; id[2] = n2;
  float nv2 = fmaxf(v[2], fminf(v[1], w));       // min3(v0,v1,w) == min(v1,w) since v1<=v0
  float nv1 = __builtin_amdgcn_fmed3f(v[0], v[1], w);
  v[0] = fmaxf(v[0], w);
  v[1] = nv1; v[2] = nv2;
}

// Expand fp32 inputs into dedup'd split-bf16 panel layout (hi|lo), ctx and main.
__global__ __launch_bounds__(256) void split_convert(const float* __restrict__ ctx,
    const float* __restrict__ mn, u16* __restrict__ ctxS, u16* __restrict__ mnS) {
  const int b = blockIdx.y;
  const int rp = blockIdx.x & 15, og = blockIdx.x >> 4;  // og 0..7
  const int tid = threadIdx.x;
  const int row = tid & 127;
  const int o = og * 2 + (tid >> 7);                     // source k-octet 0..15
  const size_t srcOff = (((size_t)b * LDIM + rp * 128 + row) * DDIM + o * 8);
  const float4 c0 = *(const float4*)(ctx + srcOff);
  const float4 c1 = *(const float4*)(ctx + srcOff + 4);
  const float4 m0 = *(const float4*)(mn + srcOff);
  const float4 m1 = *(const float4*)(mn + srcOff + 4);
  uint4 chi = make_uint4(pk2(c0.x,c0.y), pk2(c0.z,c0.w), pk2(c1.x,c1.y), pk2(c1.z,c1.w));
  uint4 clo = make_uint4(pk2(c0.x-bfhi(c0.x), c0.y-bfhi(c0.y)),
                         pk2(c0.z-bfhi(c0.z), c0.w-bfhi(c0.w)),
                         pk2(c1.x-bfhi(c1.x), c1.y-bfhi(c1.y)),
                         pk2(c1.z-bfhi(c1.z), c1.w-bfhi(c1.w)));
  uint4 mhi = make_uint4(pk2(m0.x,m0.y), pk2(m0.z,m0.w), pk2(m1.x,m1.y), pk2(m1.z,m1.w));
  uint4 mlo = make_uint4(pk2(m0.x-bfhi(m0.x), m0.y-bfhi(m0.y)),
                         pk2(m0.z-bfhi(m0.z), m0.w-bfhi(m0.w)),
                         pk2(m1.x-bfhi(m1.x), m1.y-bfhi(m1.y)),
                         pk2(m1.z-bfhi(m1.z), m1.w-bfhi(m1.w)));
  u16* dA = ctxS + ((size_t)b * 16 + rp) * PANEL_U16;
  u16* dB = mnS  + ((size_t)b * 16 + rp) * PANEL_U16;
  const int base = o * 1024 + row * 8;
  *(uint4*)(dA + base)         = chi;   // koct o      : AH
  *(uint4*)(dA + base + 16384) = clo;   // koct o + 16 : AL
  *(uint4*)(dB + base)         = mhi;   // koct o      : BH
  *(uint4*)(dB + base + 16384) = mlo;   // koct o + 16 : BL
}

// W[b][c][m] = ctx.main^T via dedup'd split-bf16 MFMA. W is NEVER stored.
// Main loop: 4 chunks of 32-K; per chunk stage AH/AL/BH/BL (8KB each) and run
// 48 MFMAs (AH.BH + AL.BH + AH.BL), fragments sequenced to cap liveness.
// Epilogue (R12-proven): quadrants staged to 64x65 LDS, whole-wave serial walks.
__global__ __launch_bounds__(256) void gemm_mfma(const u16* __restrict__ A,
    const u16* __restrict__ B, unsigned* __restrict__ rowP,
    unsigned* __restrict__ colP) {
  __shared__ __attribute__((aligned(16))) char ldsbuf[33280];
  u16* AsH = (u16*)ldsbuf;           // 8 KB (4 kocts)
  u16* AsL = AsH + 4096;             // 8 KB
  u16* BsH = AsH + 8192;             // 8 KB
  u16* BsL = AsH + 12288;            // 8 KB
  float* stg = (float*)ldsbuf;       // epilogue: 2 x 4160 floats (64x65 each)
  const int b = blockIdx.z;
  const int rp = blockIdx.y, mp = blockIdx.x;
  const int tid = threadIdx.x;
  const int w = tid >> 6, lane = tid & 63;
  const int lr = lane & 15, lg = lane >> 4;
  const int wr = w >> 1, wc = w & 1;
  const u16* srcA = A + ((size_t)b * 16 + rp) * PANEL_U16;
  const u16* srcB = B + ((size_t)b * 16 + mp) * PANEL_U16;
  f32x4 acc[4][4];
  const f32x4 zz = {0.f, 0.f, 0.f, 0.f};
  #pragma unroll
  for (int i = 0; i < 4; i++)
    #pragma unroll
    for (int j = 0; j < 4; j++) acc[i][j] = zz;

  for (int ch = 0; ch < 4; ch++) {       // 32-K chunk = kocts ch*4..ch*4+3
    if (ch) __syncthreads();
    const int co = ch * 4096;            // u16 offset of chunk in H half
    #pragma unroll
    for (int q = 0; q < 2; q++) {
      const int c = q * 256 + w * 64;    // chunk-of-16B index base for this wave
      glds16(srcA + co         + (size_t)(c + lane) * 8, AsH + c * 8);
      glds16(srcA + 16384 + co + (size_t)(c + lane) * 8, AsL + c * 8);
      glds16(srcB + co         + (size_t)(c + lane) * 8, BsH + c * 8);
      glds16(srcB + 16384 + co + (size_t)(c + lane) * 8, BsL + c * 8);
    }
    __syncthreads();
    const int ao = lg * 1024 + (wr * 64 + lr) * 8;
    const int bo = lg * 1024 + (wc * 64 + lr) * 8;
    bf16x8 aH[4], bH[4];
    #pragma unroll
    for (int i = 0; i < 4; i++) aH[i] = *(const bf16x8*)&AsH[ao + i * 128];
    #pragma unroll
    for (int j = 0; j < 4; j++) bH[j] = *(const bf16x8*)&BsH[bo + j * 128];
    #pragma unroll
    for (int i = 0; i < 4; i++)
      #pragma unroll
      for (int j = 0; j < 4; j++)
        acc[i][j] = __builtin_amdgcn_mfma_f32_16x16x32_bf16(aH[i], bH[j], acc[i][j], 0, 0, 0);
    bf16x8 aL[4];
    #pragma unroll
    for (int i = 0; i < 4; i++) aL[i] = *(const bf16x8*)&AsL[ao + i * 128];
    #pragma unroll
    for (int i = 0; i < 4; i++)
      #pragma unroll
      for (int j = 0; j < 4; j++)
        acc[i][j] = __builtin_amdgcn_mfma_f32_16x16x32_bf16(aL[i], bH[j], acc[i][j], 0, 0, 0);
    bf16x8 bL[4];
    #pragma unroll
    for (int j = 0; j < 4; j++) bL[j] = *(const bf16x8*)&BsL[bo + j * 128];
    #pragma unroll
    for (int i = 0; i < 4; i++)
      #pragma unroll
      for (int j = 0; j < 4; j++)
        acc[i][j] = __builtin_amdgcn_mfma_f32_16x16x32_bf16(aH[i], bL[j], acc[i][j], 0, 0, 0);
  }

  // ---- fused stats epilogue. C/D layout (m89, verified by R1 W-store):
  //      local row = i*16 + lg*4 + r, local col = j*16 + lr (within 64x64 quadrant).
  for (int rnd = 0; rnd < 2; rnd++) {
    __syncthreads();                       // main-loop LDS (or prev round stg) dead
    if (wr == rnd) {
      float* st = stg + wc * 4160;
      #pragma unroll
      for (int i = 0; i < 4; i++)
        #pragma unroll
        for (int r = 0; r < 4; r++) {
          const int row = i * 16 + lg * 4 + r;
          #pragma unroll
          for (int j = 0; j < 4; j++)
            st[row * 65 + j * 16 + lr] = acc[i][j][r];
        }
    }
    __syncthreads();
    {
      const int buf = tid >> 7;            // which staging buffer (== wc)
      const int role = (tid >> 6) & 1;     // 0: col reduce, 1: row reduce
      const int l6 = tid & 63;
      const float* st = stg + buf * 4160;
      float v[3] = {-3e38f,-3e38f,-3e38f}; int id[3] = {-1,-1,-1};
      float sm = 0.f, s2 = 0.f;
      if (role == 0) {
        // column l6 of this quadrant, over its 64 rows
        #pragma unroll 8
        for (int r = 0; r < 64; r++) {
          float wv = st[r * 65 + l6];
          sm += wv; s2 = fmaf(wv, wv, s2);
          ins3(wv, rp*128 + rnd*64 + r, v, id);
        }
        size_t rec = (((size_t)b*32 + rp*2 + rnd)*LDIM + mp*128 + buf*64 + l6) * 8;
        uint4 lo = make_uint4(__float_as_uint(v[0]), __float_as_uint(v[1]),
                              __float_as_uint(v[2]), __float_as_uint(sm));
        uint4 hi = make_uint4(__float_as_uint(s2), (unsigned)id[0],
                              (unsigned)id[1], (unsigned)id[2]);
        *(uint4*)(colP + rec)     = lo;
        *(uint4*)(colP + rec + 4) = hi;
      } else {
        // row l6 of this quadrant, over its 64 cols
        #pragma unroll 8
        for (int c = 0; c < 64; c++) {
          float wv = st[l6 * 65 + c];
          sm += wv; s2 = fmaf(wv, wv, s2);
          ins3(wv, mp*128 + buf*64 + c, v, id);
        }
        size_t rec = (((size_t)b*32 + mp*2 + buf)*LDIM + rp*128 + rnd*64 + l6) * 8;
        uint4 lo = make_uint4(__float_as_uint(v[0]), __float_as_uint(v[1]),
                              __float_as_uint(v[2]), __float_as_uint(sm));
        uint4 hi = make_uint4(__float_as_uint(s2), (unsigned)id[0],
                              (unsigned)id[1], (unsigned)id[2]);
        *(uint4*)(rowP + rec)     = lo;
        *(uint4*)(rowP + rec + 4) = hi;
      }
    }
  }
}

// Merge nt per-tile partials per index -> normalized top-3 weights + indices + std.
__global__ __launch_bounds__(256) void stats_combine(const unsigned* __restrict__ P,
    int nt, float* __restrict__ w3, int* __restrict__ i3, float* __restrict__ sd) {
  const int b = blockIdx.y;
  const int c = blockIdx.x * 256 + threadIdx.x;
  float v[3] = {-3e38f,-3e38f,-3e38f}; int id[3] = {-1,-1,-1};
  float sum = 0.f, sq = 0.f;
  for (int t = 0; t < nt; t++) {
    const unsigned* rec = P + (((size_t)b*nt + t)*LDIM + c) * 8;
    const uint4 lo = *(const uint4*)rec;
    const uint4 hi = *(const uint4*)(rec + 4);
    ins3(__uint_as_float(lo.x), (int)hi.y, v, id);
    ins3(__uint_as_float(lo.y), (int)hi.z, v, id);
    ins3(__uint_as_float(lo.z), (int)hi.w, v, id);
    sum += __uint_as_float(lo.w); sq += __uint_as_float(hi.x);
  }
  float inv = 1.f/(v[0]+v[1]+v[2]);
  size_t o = (size_t)b*LDIM + c;
  w3[o*3+0]=v[0]*inv; w3[o*3+1]=v[1]*inv; w3[o*3+2]=v[2]*inv;
  i3[o*3+0]=id[0]; i3[o*3+1]=id[1]; i3[o*3+2]=id[2];
  float mean = sum * (1.f/LDIM);
  float var = sq*(1.f/LDIM) - mean*mean;
  sd[o] = sqrtf(fmaxf(var, 0.f));
}

// att_merge_c[m][d] += wk_c[c][m] * ctx[c][d]  -- 3 targets per row c (scatter).
__global__ __launch_bounds__(128) void scatter_att(const float* __restrict__ ctx,
    const float* __restrict__ rw, const int* __restrict__ ri,
    float* __restrict__ attC) {
  const int b = blockIdx.y, c = blockIdx.x, d = threadIdx.x;
  const size_t base = (size_t)b*LDIM + c;
  const float x = ctx[base*DDIM + d];
  #pragma unroll
  for (int t = 0; t < 3; t++) {
    float w = rw[base*3 + t];
    int m = ri[base*3 + t];
    atomicAdd(&attC[((size_t)b*LDIM + m)*DDIM + d], w*x);
  }
}

// outputs_c = |ctx - gather(col top-3 of main)| * row_std   -> bf16
// outputs_m = |main - attC| * col_std                       -> bf16
// 4 rows/block, float2 per lane (8B loads), packed u32 stores.
__global__ __launch_bounds__(256) void make_outputs(const float* __restrict__ ctx,
    const float* __restrict__ mn, const float* __restrict__ attC,
    const float* __restrict__ rs, const float* __restrict__ cw,
    const int* __restrict__ ci, const float* __restrict__ cs,
    u16* __restrict__ outCb, u16* __restrict__ outMb) {
  const int b = blockIdx.y;
  const int i = blockIdx.x * 4 + (threadIdx.x >> 6);
  const int d2 = (threadIdx.x & 63) * 2;
  const size_t base = (size_t)b*LDIM + i;
  const float2 cx = *(const float2*)&ctx[base*DDIM + d2];
  const float2 mm = *(const float2*)&mn[base*DDIM + d2];
  const float2 ac = *(const float2*)&attC[base*DDIM + d2];
  float am0 = 0.f, am1 = 0.f;
  #pragma unroll
  for (int t = 0; t < 3; t++) {
    float w = cw[base*3 + t];
    const float2 g = *(const float2*)&mn[((size_t)b*LDIM + ci[base*3+t])*DDIM + d2];
    am0 += w * g.x; am1 += w * g.y;
  }
  const float rsv = rs[base], csv = cs[base];
  float oc0 = fabsf(cx.x - am0) * rsv, oc1 = fabsf(cx.y - am1) * rsv;
  float om0 = fabsf(mm.x - ac.x) * csv, om1 = fabsf(mm.y - ac.y) * csv;
  *(unsigned*)&outCb[base*DDIM + d2] = pk2(oc0, oc1);
  *(unsigned*)&outMb[base*DDIM + d2] = pk2(om0, om1);
}

// Convert conv weights to bf16 panel wB[ko 0..47][f 0..111][e 0..7]:
// wB[ko][f][e] = w[ks = ko/16][d = (ko%16)*8 + e][f], f >= FDIM -> 0.
__global__ __launch_bounds__(256) void conv_prep_w(const float* __restrict__ wv,
    u16* __restrict__ wB) {
  int idx = blockIdx.x * 256 + threadIdx.x;
  if (idx >= 48 * FPAD * 8) return;
  int e = idx & 7, f = (idx >> 3) % FPAD, ko = idx / (FPAD * 8);
  int ks = ko >> 4, d = ((ko & 15) << 3) | e;
  float val = (f < FDIM) ? wv[(ks * DDIM + d) * FDIM + f] : 0.f;
  wB[idx] = (u16)f2bfu(val);
}

// conv1d(KS=3) + bias + relu + maxpool as MFMA GEMM: y[t,f] = sum_k X[t+ks,d]*w[ks,d,f].
// Block: 256 thr = 4 waves, covers CT=64 t-rows x all 112 f. K=384 -> 12 MFMA/f-tile.
__global__ __launch_bounds__(256) void conv_mfma(const u16* __restrict__ XCb,
    const u16* __restrict__ XMb, const u16* __restrict__ wB,
    const float* __restrict__ bias, float* __restrict__ out) {
  const int b = blockIdx.y, z = blockIdx.z;
  const int t0 = blockIdx.x * CT;
  const u16* X = (z == 0 ? XCb : XMb) + (size_t)b * LDIM * DDIM;
  __shared__ u16 Xs[(CT + 2) * 128];   // rows of 256B, XOR-swizzled
  __shared__ float smax[FPAD];
  const int tid = threadIdx.x;
  for (int e = tid; e < (CT + 2) * 16; e += 256) {
    int row = e >> 4, c16 = e & 15;
    int t = t0 + row;
    uint4 val = (t < LDIM) ? *(const uint4*)&X[(size_t)t * DDIM + c16 * 8]
                           : make_uint4(0u, 0u, 0u, 0u);
    int byte = row * 256 + ((c16 * 16) ^ ((row & 7) << 4));
    *(uint4*)((char*)Xs + byte) = val;
  }
  if (tid < FPAD) smax[tid] = 0.f;
  __syncthreads();
  const int w = tid >> 6, lane = tid & 63;
  const int lr = lane & 15, lg = lane >> 4;
  const int lt0 = w * 16;
  bf16x8 av[12];
  #pragma unroll
  for (int kk = 0; kk < 12; kk++) {
    int ko = kk * 4 + lg;          // k-octet 0..47; k = ko*8+e
    int ks = ko >> 4, d8 = ko & 15;
    int row = lt0 + lr + ks;
    int byte = row * 256 + ((d8 * 16) ^ ((row & 7) << 4));
    av[kk] = *(const bf16x8*)((const char*)Xs + byte);
  }
  for (int ft = 0; ft < 7; ft++) {
    f32x4 acc = {0.f, 0.f, 0.f, 0.f};
    #pragma unroll
    for (int kk = 0; kk < 12; kk++) {
      int ko = kk * 4 + lg;
      bf16x8 bv = *(const bf16x8*)&wB[((size_t)ko * FPAD + ft * 16 + lr) * 8];
      acc = __builtin_amdgcn_mfma_f32_16x16x32_bf16(av[kk], bv, acc, 0, 0, 0);
    }
    int f = ft * 16 + lr;
    float bb = (f < FDIM) ? bias[f] : 0.f;
    float mx = 0.f;
    #pragma unroll
    for (int r = 0; r < 4; r++) {
      int t = t0 + lt0 + lg * 4 + r;
      float y = fmaxf(acc[r] + bb, 0.f);
      if (t <= LDIM - 3) mx = fmaxf(mx, y);   // invalid t -> 0 (safe: relu-max >= 0)
    }
    mx = fmaxf(mx, __shfl_xor(mx, 16));
    mx = fmaxf(mx, __shfl_xor(mx, 32));
    if (lg == 0 && f < FDIM)
      atomicMax((unsigned*)&smax[f], __float_as_uint(mx));
  }
  __syncthreads();
  if (tid < FDIM)
    atomicMax((unsigned*)&out[(size_t)b * (2 * FDIM) + z * FDIM + tid],
              __float_as_uint(smax[tid]));
}

extern "C" void kernel_launch(void* const* d_in, const int* in_sizes, int n_in,
                              void* d_out, int out_size, void* d_ws, size_t ws_size,
                              hipStream_t stream) {
  const float* ctx   = (const float*)d_in[0];
  const float* mn    = (const float*)d_in[1];
  const float* wconv = (const float*)d_in[2];
  const float* bias  = (const float*)d_in[3];
  float* out = (float*)d_out;

  // pool accumulators must start at 0 (d_out is poisoned before every call)
  hipMemsetAsync(d_out, 0, sizeof(float)*(size_t)out_size, stream);

  // Workspace: [wB bf16 weight panel: 64K floats reserved] then per-iteration arrays.
  const size_t wbFloats = 65536;
  // Per-batch (floats/dwords) -- W is never materialized:
  //   row partial records:  32*L*8     = 524288
  //   col partial records:  32*L*8     = 524288
  //   final stats:          14*L       = 28672
  //   attC:                 L*D        = 262144
  //   outCb+outMb (u16):    2*L*D u16  = 262144 float-equiv
  //   split-bf16 panels:    2*16*PANEL_U16/2 = 524288
  const size_t perBatchFloats = (size_t)32*LDIM*8 + (size_t)32*LDIM*8
                              + 14*(size_t)LDIM + (size_t)LDIM*DDIM + (size_t)LDIM*DDIM
                              + 2*(size_t)16*PANEL_U16/2;
  const size_t perBatchBytes = perBatchFloats * sizeof(float);
  int nbMax = (int)((ws_size - wbFloats*sizeof(float)) / perBatchBytes);
  if (nbMax < 1) nbMax = 1;
  if (nbMax > BDIM) nbMax = BDIM;

  u16* wB = (u16*)d_ws;
  float* iterBase = (float*)d_ws + wbFloats;
  conv_prep_w<<<dim3((48*FPAD*8 + 255)/256), 256, 0, stream>>>(wconv, wB);

  for (int b0 = 0; b0 < BDIM; b0 += nbMax) {
    const int nb = (BDIM - b0 < nbMax) ? (BDIM - b0) : nbMax;
    unsigned* rowP = (unsigned*)iterBase;
    unsigned* colP = rowP + (size_t)nb*32*LDIM*8;
    float* rowW = (float*)(colP + (size_t)nb*32*LDIM*8);
    int*   rowI = (int*)(rowW + (size_t)nb*LDIM*3);
    float* rowS = (float*)(rowI + (size_t)nb*LDIM*3);
    float* colW = rowS + (size_t)nb*LDIM;
    int*   colI = (int*)(colW + (size_t)nb*LDIM*3);
    float* colS = (float*)(colI + (size_t)nb*LDIM*3);
    float* attC = colS + (size_t)nb*LDIM;
    u16*   outCb = (u16*)(attC + (size_t)nb*LDIM*DDIM);
    u16*   outMb = outCb + (size_t)nb*LDIM*DDIM;
    u16*   ctxS = outMb + (size_t)nb*LDIM*DDIM;
    u16*   mnS  = ctxS + (size_t)nb*16*PANEL_U16;
    const float* ctxb = ctx + (size_t)b0*LDIM*DDIM;
    const float* mnb  = mn  + (size_t)b0*LDIM*DDIM;

    split_convert<<<dim3(128, nb), 256, 0, stream>>>(ctxb, mnb, ctxS, mnS);
    gemm_mfma<<<dim3(LDIM/128, LDIM/128, nb), 256, 0, stream>>>(
        ctxS, mnS, rowP, colP);
    stats_combine<<<dim3(LDIM/256, nb), 256, 0, stream>>>(rowP, 32, rowW, rowI, rowS);
    stats_combine<<<dim3(LDIM/256, nb), 256, 0, stream>>>(colP, 32, colW, colI, colS);
    hipMemsetAsync(attC, 0, (size_t)nb*LDIM*DDIM*sizeof(float), stream);
    scatter_att<<<dim3(LDIM, nb), 128, 0, stream>>>(ctxb, rowW, rowI, attC);
    make_outputs<<<dim3(LDIM/4, nb), 256, 0, stream>>>(ctxb, mnb, attC, rowS, colW, colI, colS, outCb, outMb);
    conv_mfma<<<dim3(LDIM/CT, nb, 2), 256, 0, stream>>>(
        outCb, outMb, wB, bias, out + (size_t)b0*2*FDIM);
  }
}

// Round 18
// 267.176 us; speedup vs baseline: 1.3530x; 1.0904x over previous
//
#include <hip/hip_runtime.h>
#include <math.h>

#define LDIM 2048
#define DDIM 128
#define BDIM 16
#define FDIM 100
// Split-K bf16 GEMM, dedup'd panels: A' = [AH | AL], B' = [BH | BL] (K=256 stored).
// Per 32-K chunk the 3 Markidis products are computed explicitly:
//   acc += AH.BH + AL.BH + AH.BL   (== fp32 ctx.main^T to ~1e-4)
// Panel layout per (batch,row-panel): [32 koct][128 row][8 elems] bf16.
#define PANEL_U16 (32 * 1024)
// conv-as-GEMM: K = 3*128 = 384, N = 112 (100 filters padded to 7 tiles of 16)
#define FPAD 112
#define CT 64            // t-rows per conv block

typedef unsigned short u16;
typedef __bf16 bf16x8 __attribute__((ext_vector_type(8)));
typedef float f32x4 __attribute__((ext_vector_type(4)));

__device__ inline unsigned f2bfu(float x) {  // fp32 -> bf16 bits, RNE
  unsigned u = __float_as_uint(x);
  return (u + 0x7FFFu + ((u >> 16) & 1u)) >> 16;
}
__device__ inline unsigned pk2(float a, float b) {
  return f2bfu(a) | (f2bfu(b) << 16);
}
__device__ inline float bfhi(float x) {  // value of the bf16 hi part
  return __uint_as_float(f2bfu(x) << 16);
}

__device__ inline void glds16(const u16* g, u16* l) {
  __builtin_amdgcn_global_load_lds(
      (const __attribute__((address_space(1))) void*)g,
      (__attribute__((address_space(3))) void*)l, 16, 0, 0);
}

// Exact top-3 insert, med3-accelerated. Values (4 ops, exact fp32):
//   v0' = max(v0,w); v1' = med3(v0,v1,w); v2' = max(v2, min(v1,w))
// Indices: 3 exact fp32 compares + 5 selects. NO value approximation --
// R10/R15 proved index selection needs full fp32 resolution of W.
__device__ inline void ins3(float w, int idx, float v[3], int id[3]) {
  bool c0 = w > v[0], c1 = w > v[1], c2 = w > v[2];
  int n0 = c0 ? idx : id[0];
  int n1 = c0 ? id[0] : (c1 ? idx : id[1]);
  int n2 = c1 ? id[1] : (c2 ? idx : id[2]);
  id[0] = n0; id[1] = n1; id[2] = n2;
  float nv2 = fmaxf(v[2], fminf(v[1], w));       // min3(v0,v1,w) == min(v1,w) since v1<=v0
  float nv1 = __builtin_amdgcn_fmed3f(v[0], v[1], w);
  v[0] = fmaxf(v[0], w);
  v[1] = nv1; v[2] = nv2;
}

// Expand fp32 inputs into dedup'd split-bf16 panel layout (hi|lo), ctx and main.
__global__ __launch_bounds__(256) void split_convert(const float* __restrict__ ctx,
    const float* __restrict__ mn, u16* __restrict__ ctxS, u16* __restrict__ mnS) {
  const int b = blockIdx.y;
  const int rp = blockIdx.x & 15, og = blockIdx.x >> 4;  // og 0..7
  const int tid = threadIdx.x;
  const int row = tid & 127;
  const int o = og * 2 + (tid >> 7);                     // source k-octet 0..15
  const size_t srcOff = (((size_t)b * LDIM + rp * 128 + row) * DDIM + o * 8);
  const float4 c0 = *(const float4*)(ctx + srcOff);
  const float4 c1 = *(const float4*)(ctx + srcOff + 4);
  const float4 m0 = *(const float4*)(mn + srcOff);
  const float4 m1 = *(const float4*)(mn + srcOff + 4);
  uint4 chi = make_uint4(pk2(c0.x,c0.y), pk2(c0.z,c0.w), pk2(c1.x,c1.y), pk2(c1.z,c1.w));
  uint4 clo = make_uint4(pk2(c0.x-bfhi(c0.x), c0.y-bfhi(c0.y)),
                         pk2(c0.z-bfhi(c0.z), c0.w-bfhi(c0.w)),
                         pk2(c1.x-bfhi(c1.x), c1.y-bfhi(c1.y)),
                         pk2(c1.z-bfhi(c1.z), c1.w-bfhi(c1.w)));
  uint4 mhi = make_uint4(pk2(m0.x,m0.y), pk2(m0.z,m0.w), pk2(m1.x,m1.y), pk2(m1.z,m1.w));
  uint4 mlo = make_uint4(pk2(m0.x-bfhi(m0.x), m0.y-bfhi(m0.y)),
                         pk2(m0.z-bfhi(m0.z), m0.w-bfhi(m0.w)),
                         pk2(m1.x-bfhi(m1.x), m1.y-bfhi(m1.y)),
                         pk2(m1.z-bfhi(m1.z), m1.w-bfhi(m1.w)));
  u16* dA = ctxS + ((size_t)b * 16 + rp) * PANEL_U16;
  u16* dB = mnS  + ((size_t)b * 16 + rp) * PANEL_U16;
  const int base = o * 1024 + row * 8;
  *(uint4*)(dA + base)         = chi;   // koct o      : AH
  *(uint4*)(dA + base + 16384) = clo;   // koct o + 16 : AL
  *(uint4*)(dB + base)         = mhi;   // koct o      : BH
  *(uint4*)(dB + base + 16384) = mlo;   // koct o + 16 : BL
}

// W[b][c][m] = ctx.main^T via dedup'd split-bf16 MFMA. W is NEVER stored.
// Main loop: 4 chunks of 32-K; per chunk stage AH/AL/BH/BL (8KB each) and run
// 48 MFMAs (AH.BH + AL.BH + AH.BL), fragments sequenced to cap liveness.
// Epilogue (R12-proven): quadrants staged to 64x65 LDS, whole-wave serial walks.
__global__ __launch_bounds__(256) void gemm_mfma(const u16* __restrict__ A,
    const u16* __restrict__ B, unsigned* __restrict__ rowP,
    unsigned* __restrict__ colP) {
  __shared__ __attribute__((aligned(16))) char ldsbuf[33280];
  u16* AsH = (u16*)ldsbuf;           // 8 KB (4 kocts)
  u16* AsL = AsH + 4096;             // 8 KB
  u16* BsH = AsH + 8192;             // 8 KB
  u16* BsL = AsH + 12288;            // 8 KB
  float* stg = (float*)ldsbuf;       // epilogue: 2 x 4160 floats (64x65 each)
  const int b = blockIdx.z;
  const int rp = blockIdx.y, mp = blockIdx.x;
  const int tid = threadIdx.x;
  const int w = tid >> 6, lane = tid & 63;
  const int lr = lane & 15, lg = lane >> 4;
  const int wr = w >> 1, wc = w & 1;
  const u16* srcA = A + ((size_t)b * 16 + rp) * PANEL_U16;
  const u16* srcB = B + ((size_t)b * 16 + mp) * PANEL_U16;
  f32x4 acc[4][4];
  const f32x4 zz = {0.f, 0.f, 0.f, 0.f};
  #pragma unroll
  for (int i = 0; i < 4; i++)
    #pragma unroll
    for (int j = 0; j < 4; j++) acc[i][j] = zz;

  for (int ch = 0; ch < 4; ch++) {       // 32-K chunk = kocts ch*4..ch*4+3
    if (ch) __syncthreads();
    const int co = ch * 4096;            // u16 offset of chunk in H half
    #pragma unroll
    for (int q = 0; q < 2; q++) {
      const int c = q * 256 + w * 64;    // chunk-of-16B index base for this wave
      glds16(srcA + co         + (size_t)(c + lane) * 8, AsH + c * 8);
      glds16(srcA + 16384 + co + (size_t)(c + lane) * 8, AsL + c * 8);
      glds16(srcB + co         + (size_t)(c + lane) * 8, BsH + c * 8);
      glds16(srcB + 16384 + co + (size_t)(c + lane) * 8, BsL + c * 8);
    }
    __syncthreads();
    const int ao = lg * 1024 + (wr * 64 + lr) * 8;
    const int bo = lg * 1024 + (wc * 64 + lr) * 8;
    bf16x8 aH[4], bH[4];
    #pragma unroll
    for (int i = 0; i < 4; i++) aH[i] = *(const bf16x8*)&AsH[ao + i * 128];
    #pragma unroll
    for (int j = 0; j < 4; j++) bH[j] = *(const bf16x8*)&BsH[bo + j * 128];
    #pragma unroll
    for (int i = 0; i < 4; i++)
      #pragma unroll
      for (int j = 0; j < 4; j++)
        acc[i][j] = __builtin_amdgcn_mfma_f32_16x16x32_bf16(aH[i], bH[j], acc[i][j], 0, 0, 0);
    bf16x8 aL[4];
    #pragma unroll
    for (int i = 0; i < 4; i++) aL[i] = *(const bf16x8*)&AsL[ao + i * 128];
    #pragma unroll
    for (int i = 0; i < 4; i++)
      #pragma unroll
      for (int j = 0; j < 4; j++)
        acc[i][j] = __builtin_amdgcn_mfma_f32_16x16x32_bf16(aL[i], bH[j], acc[i][j], 0, 0, 0);
    bf16x8 bL[4];
    #pragma unroll
    for (int j = 0; j < 4; j++) bL[j] = *(const bf16x8*)&BsL[bo + j * 128];
    #pragma unroll
    for (int i = 0; i < 4; i++)
      #pragma unroll
      for (int j = 0; j < 4; j++)
        acc[i][j] = __builtin_amdgcn_mfma_f32_16x16x32_bf16(aH[i], bL[j], acc[i][j], 0, 0, 0);
  }

  // ---- fused stats epilogue. C/D layout (m89, verified by R1 W-store):
  //      local row = i*16 + lg*4 + r, local col = j*16 + lr (within 64x64 quadrant).
  for (int rnd = 0; rnd < 2; rnd++) {
    __syncthreads();                       // main-loop LDS (or prev round stg) dead
    if (wr == rnd) {
      float* st = stg + wc * 4160;
      #pragma unroll
      for (int i = 0; i < 4; i++)
        #pragma unroll
        for (int r = 0; r < 4; r++) {
          const int row = i * 16 + lg * 4 + r;
          #pragma unroll
          for (int j = 0; j < 4; j++)
            st[row * 65 + j * 16 + lr] = acc[i][j][r];
        }
    }
    __syncthreads();
    {
      const int buf = tid >> 7;            // which staging buffer (== wc)
      const int role = (tid >> 6) & 1;     // 0: col reduce, 1: row reduce
      const int l6 = tid & 63;
      const float* st = stg + buf * 4160;
      float v[3] = {-3e38f,-3e38f,-3e38f}; int id[3] = {-1,-1,-1};
      float sm = 0.f, s2 = 0.f;
      if (role == 0) {
        // column l6 of this quadrant, over its 64 rows
        #pragma unroll 8
        for (int r = 0; r < 64; r++) {
          float wv = st[r * 65 + l6];
          sm += wv; s2 = fmaf(wv, wv, s2);
          ins3(wv, rp*128 + rnd*64 + r, v, id);
        }
        size_t rec = (((size_t)b*32 + rp*2 + rnd)*LDIM + mp*128 + buf*64 + l6) * 8;
        uint4 lo = make_uint4(__float_as_uint(v[0]), __float_as_uint(v[1]),
                              __float_as_uint(v[2]), __float_as_uint(sm));
        uint4 hi = make_uint4(__float_as_uint(s2), (unsigned)id[0],
                              (unsigned)id[1], (unsigned)id[2]);
        *(uint4*)(colP + rec)     = lo;
        *(uint4*)(colP + rec + 4) = hi;
      } else {
        // row l6 of this quadrant, over its 64 cols
        #pragma unroll 8
        for (int c = 0; c < 64; c++) {
          float wv = st[l6 * 65 + c];
          sm += wv; s2 = fmaf(wv, wv, s2);
          ins3(wv, mp*128 + buf*64 + c, v, id);
        }
        size_t rec = (((size_t)b*32 + mp*2 + buf)*LDIM + rp*128 + rnd*64 + l6) * 8;
        uint4 lo = make_uint4(__float_as_uint(v[0]), __float_as_uint(v[1]),
                              __float_as_uint(v[2]), __float_as_uint(sm));
        uint4 hi = make_uint4(__float_as_uint(s2), (unsigned)id[0],
                              (unsigned)id[1], (unsigned)id[2]);
        *(uint4*)(rowP + rec)     = lo;
        *(uint4*)(rowP + rec + 4) = hi;
      }
    }
  }
}

// Merge 32 per-tile partials per index; z=0 -> row stats, z=1 -> col stats.
__global__ __launch_bounds__(256) void stats_combine(const unsigned* __restrict__ rowP,
    const unsigned* __restrict__ colP,
    float* __restrict__ rw, int* __restrict__ ri, float* __restrict__ rs,
    float* __restrict__ cw, int* __restrict__ ci, float* __restrict__ cs) {
  const int b = blockIdx.y;
  const int c = blockIdx.x * 256 + threadIdx.x;
  const unsigned* P = blockIdx.z == 0 ? rowP : colP;
  float* w3 = blockIdx.z == 0 ? rw : cw;
  int*   i3 = blockIdx.z == 0 ? ri : ci;
  float* sd = blockIdx.z == 0 ? rs : cs;
  float v[3] = {-3e38f,-3e38f,-3e38f}; int id[3] = {-1,-1,-1};
  float sum = 0.f, sq = 0.f;
  for (int t = 0; t < 32; t++) {
    const unsigned* rec = P + (((size_t)b*32 + t)*LDIM + c) * 8;
    const uint4 lo = *(const uint4*)rec;
    const uint4 hi = *(const uint4*)(rec + 4);
    ins3(__uint_as_float(lo.x), (int)hi.y, v, id);
    ins3(__uint_as_float(lo.y), (int)hi.z, v, id);
    ins3(__uint_as_float(lo.z), (int)hi.w, v, id);
    sum += __uint_as_float(lo.w); sq += __uint_as_float(hi.x);
  }
  float inv = 1.f/(v[0]+v[1]+v[2]);
  size_t o = (size_t)b*LDIM + c;
  w3[o*3+0]=v[0]*inv; w3[o*3+1]=v[1]*inv; w3[o*3+2]=v[2]*inv;
  i3[o*3+0]=id[0]; i3[o*3+1]=id[1]; i3[o*3+2]=id[2];
  float mean = sum * (1.f/LDIM);
  float var = sq*(1.f/LDIM) - mean*mean;
  sd[o] = sqrtf(fmaxf(var, 0.f));
}

// att_merge_c[m][d] += wk_c[c][m] * ctx[c][d]  -- 3 targets per row c (scatter).
__global__ __launch_bounds__(128) void scatter_att(const float* __restrict__ ctx,
    const float* __restrict__ rw, const int* __restrict__ ri,
    float* __restrict__ attC) {
  const int b = blockIdx.y, c = blockIdx.x, d = threadIdx.x;
  const size_t base = (size_t)b*LDIM + c;
  const float x = ctx[base*DDIM + d];
  #pragma unroll
  for (int t = 0; t < 3; t++) {
    float w = rw[base*3 + t];
    int m = ri[base*3 + t];
    atomicAdd(&attC[((size_t)b*LDIM + m)*DDIM + d], w*x);
  }
}

// Convert conv weights to bf16 panel wB[ko 0..47][f 0..111][e 0..7]:
// wB[ko][f][e] = w[ks = ko/16][d = (ko%16)*8 + e][f], f >= FDIM -> 0.
__global__ __launch_bounds__(256) void conv_prep_w(const float* __restrict__ wv,
    u16* __restrict__ wB) {
  int idx = blockIdx.x * 256 + threadIdx.x;
  if (idx >= 48 * FPAD * 8) return;
  int e = idx & 7, f = (idx >> 3) % FPAD, ko = idx / (FPAD * 8);
  int ks = ko >> 4, d = ((ko & 15) << 3) | e;
  float val = (f < FDIM) ? wv[(ks * DDIM + d) * FDIM + f] : 0.f;
  wB[idx] = (u16)f2bfu(val);
}

// FUSED make_outputs + conv1d(KS=3) + bias + relu + maxpool (MFMA GEMM).
// The conv block computes its own 66 X-rows directly into the swizzled LDS tile:
//   z=0: X[t][d] = |ctx[t][d] - sum_k cw[t,k]*mn[ci[t,k]][d]| * rs[t]   (outputs_c)
//   z=1: X[t][d] = |mn[t][d] - attC[t][d]| * cs[t]                      (outputs_m)
// No global outC/outM buffers. Halo rows (2/64) recomputed. Per-row scalars are
// wave-uniform broadcasts. Then 12 MFMA/f-tile over K=384 as before.
__global__ __launch_bounds__(256) void conv_mfma(const float* __restrict__ ctx,
    const float* __restrict__ mn, const float* __restrict__ attC,
    const float* __restrict__ rs, const float* __restrict__ cw,
    const int* __restrict__ ci, const float* __restrict__ cs,
    const u16* __restrict__ wB, const float* __restrict__ bias,
    float* __restrict__ out) {
  const int b = blockIdx.y, z = blockIdx.z;
  const int t0 = blockIdx.x * CT;
  __shared__ u16 Xs[(CT + 2) * 128];   // rows of 256B, XOR-swizzled
  __shared__ float smax[FPAD];
  const int tid = threadIdx.x;
  for (int e = tid; e < (CT + 2) * 64; e += 256) {
    int row = e >> 6, p = e & 63;      // p = float2-pair index 0..63
    int t = t0 + row;
    int d2 = p * 2;
    float x0 = 0.f, x1 = 0.f;
    if (t < LDIM) {
      const size_t base = (size_t)b * LDIM + t;
      if (z == 0) {
        const float2 cx = *(const float2*)&ctx[base * DDIM + d2];
        float am0 = 0.f, am1 = 0.f;
        #pragma unroll
        for (int k = 0; k < 3; k++) {
          float wv = cw[base * 3 + k];
          const float2 g = *(const float2*)&mn[((size_t)b * LDIM + ci[base * 3 + k]) * DDIM + d2];
          am0 += wv * g.x; am1 += wv * g.y;
        }
        const float rsv = rs[base];
        x0 = fabsf(cx.x - am0) * rsv; x1 = fabsf(cx.y - am1) * rsv;
      } else {
        const float2 mm = *(const float2*)&mn[base * DDIM + d2];
        const float2 ac = *(const float2*)&attC[base * DDIM + d2];
        const float csv = cs[base];
        x0 = fabsf(mm.x - ac.x) * csv; x1 = fabsf(mm.y - ac.y) * csv;
      }
    }
    int c16 = p >> 2, q4 = p & 3;
    int byte = row * 256 + ((c16 * 16) ^ ((row & 7) << 4)) + q4 * 4;
    *(unsigned*)((char*)Xs + byte) = pk2(x0, x1);
  }
  if (tid < FPAD) smax[tid] = 0.f;
  __syncthreads();
  const int w = tid >> 6, lane = tid & 63;
  const int lr = lane & 15, lg = lane >> 4;
  const int lt0 = w * 16;
  bf16x8 av[12];
  #pragma unroll
  for (int kk = 0; kk < 12; kk++) {
    int ko = kk * 4 + lg;          // k-octet 0..47; k = ko*8+e
    int ks = ko >> 4, d8 = ko & 15;
    int row = lt0 + lr + ks;
    int byte = row * 256 + ((d8 * 16) ^ ((row & 7) << 4));
    av[kk] = *(const bf16x8*)((const char*)Xs + byte);
  }
  for (int ft = 0; ft < 7; ft++) {
    f32x4 acc = {0.f, 0.f, 0.f, 0.f};
    #pragma unroll
    for (int kk = 0; kk < 12; kk++) {
      int ko = kk * 4 + lg;
      bf16x8 bv = *(const bf16x8*)&wB[((size_t)ko * FPAD + ft * 16 + lr) * 8];
      acc = __builtin_amdgcn_mfma_f32_16x16x32_bf16(av[kk], bv, acc, 0, 0, 0);
    }
    int f = ft * 16 + lr;
    float bb = (f < FDIM) ? bias[f] : 0.f;
    float mx = 0.f;
    #pragma unroll
    for (int r = 0; r < 4; r++) {
      int t = t0 + lt0 + lg * 4 + r;
      float y = fmaxf(acc[r] + bb, 0.f);
      if (t <= LDIM - 3) mx = fmaxf(mx, y);   // invalid t -> 0 (safe: relu-max >= 0)
    }
    mx = fmaxf(mx, __shfl_xor(mx, 16));
    mx = fmaxf(mx, __shfl_xor(mx, 32));
    if (lg == 0 && f < FDIM)
      atomicMax((unsigned*)&smax[f], __float_as_uint(mx));
  }
  __syncthreads();
  if (tid < FDIM)
    atomicMax((unsigned*)&out[(size_t)b * (2 * FDIM) + z * FDIM + tid],
              __float_as_uint(smax[tid]));
}

extern "C" void kernel_launch(void* const* d_in, const int* in_sizes, int n_in,
                              void* d_out, int out_size, void* d_ws, size_t ws_size,
                              hipStream_t stream) {
  const float* ctx   = (const float*)d_in[0];
  const float* mn    = (const float*)d_in[1];
  const float* wconv = (const float*)d_in[2];
  const float* bias  = (const float*)d_in[3];
  float* out = (float*)d_out;

  // pool accumulators must start at 0 (d_out is poisoned before every call)
  hipMemsetAsync(d_out, 0, sizeof(float)*(size_t)out_size, stream);

  // Workspace: [wB bf16 weight panel: 64K floats reserved] then per-iteration arrays.
  const size_t wbFloats = 65536;
  // Per-batch (floats/dwords) -- W, outC, outM never materialized:
  //   row partial records:  32*L*8     = 524288
  //   col partial records:  32*L*8     = 524288
  //   final stats:          14*L       = 28672
  //   attC:                 L*D        = 262144
  //   split-bf16 panels:    2*16*PANEL_U16/2 = 524288
  const size_t perBatchFloats = (size_t)32*LDIM*8 + (size_t)32*LDIM*8
                              + 14*(size_t)LDIM + (size_t)LDIM*DDIM
                              + 2*(size_t)16*PANEL_U16/2;
  const size_t perBatchBytes = perBatchFloats * sizeof(float);
  int nbMax = (int)((ws_size - wbFloats*sizeof(float)) / perBatchBytes);
  if (nbMax < 1) nbMax = 1;
  if (nbMax > BDIM) nbMax = BDIM;

  u16* wB = (u16*)d_ws;
  float* iterBase = (float*)d_ws + wbFloats;
  conv_prep_w<<<dim3((48*FPAD*8 + 255)/256), 256, 0, stream>>>(wconv, wB);

  for (int b0 = 0; b0 < BDIM; b0 += nbMax) {
    const int nb = (BDIM - b0 < nbMax) ? (BDIM - b0) : nbMax;
    unsigned* rowP = (unsigned*)iterBase;
    unsigned* colP = rowP + (size_t)nb*32*LDIM*8;
    float* rowW = (float*)(colP + (size_t)nb*32*LDIM*8);
    int*   rowI = (int*)(rowW + (size_t)nb*LDIM*3);
    float* rowS = (float*)(rowI + (size_t)nb*LDIM*3);
    float* colW = rowS + (size_t)nb*LDIM;
    int*   colI = (int*)(colW + (size_t)nb*LDIM*3);
    float* colS = (float*)(colI + (size_t)nb*LDIM*3);
    float* attC = colS + (size_t)nb*LDIM;
    u16*   ctxS = (u16*)(attC + (size_t)nb*LDIM*DDIM);
    u16*   mnS  = ctxS + (size_t)nb*16*PANEL_U16;
    const float* ctxb = ctx + (size_t)b0*LDIM*DDIM;
    const float* mnb  = mn  + (size_t)b0*LDIM*DDIM;

    split_convert<<<dim3(128, nb), 256, 0, stream>>>(ctxb, mnb, ctxS, mnS);
    gemm_mfma<<<dim3(LDIM/128, LDIM/128, nb), 256, 0, stream>>>(
        ctxS, mnS, rowP, colP);
    stats_combine<<<dim3(LDIM/256, nb, 2), 256, 0, stream>>>(
        rowP, colP, rowW, rowI, rowS, colW, colI, colS);
    hipMemsetAsync(attC, 0, (size_t)nb*LDIM*DDIM*sizeof(float), stream);
    scatter_att<<<dim3(LDIM, nb), 128, 0, stream>>>(ctxb, rowW, rowI, attC);
    conv_mfma<<<dim3(LDIM/CT, nb, 2), 256, 0, stream>>>(
        ctxb, mnb, attC, rowS, colW, colI, colS, wB, bias, out + (size_t)b0*2*FDIM);
  }
}

// Round 19
// 264.015 us; speedup vs baseline: 1.3692x; 1.0120x over previous
//
#include <hip/hip_runtime.h>
#include <math.h>

#define LDIM 2048
#define DDIM 128
#define BDIM 16
#define FDIM 100
// Split-K bf16 GEMM, dedup'd panels: A' = [AH | AL], B' = [BH | BL] (K=256 stored).
// Per 32-K chunk the 3 Markidis products are computed explicitly:
//   acc += AH.BH + AL.BH + AH.BL   (== fp32 ctx.main^T to ~1e-4)
// Panel layout per (batch,row-panel): [32 koct][128 row][8 elems] bf16.
#define PANEL_U16 (32 * 1024)
// conv-as-GEMM: K = 3*128 = 384, N = 112 (100 filters padded to 7 tiles of 16)
#define FPAD 112
#define CT 64            // t-rows per conv block

typedef unsigned short u16;
typedef __bf16 bf16x8 __attribute__((ext_vector_type(8)));
typedef float f32x4 __attribute__((ext_vector_type(4)));

__device__ inline unsigned f2bfu(float x) {  // fp32 -> bf16 bits, RNE
  unsigned u = __float_as_uint(x);
  return (u + 0x7FFFu + ((u >> 16) & 1u)) >> 16;
}
__device__ inline unsigned pk2(float a, float b) {
  return f2bfu(a) | (f2bfu(b) << 16);
}
__device__ inline float bfhi(float x) {  // value of the bf16 hi part
  return __uint_as_float(f2bfu(x) << 16);
}

__device__ inline void glds16(const u16* g, u16* l) {
  __builtin_amdgcn_global_load_lds(
      (const __attribute__((address_space(1))) void*)g,
      (__attribute__((address_space(3))) void*)l, 16, 0, 0);
}

// Exact top-3 insert, med3-accelerated. Values (4 ops, exact fp32):
//   v0' = max(v0,w); v1' = med3(v0,v1,w); v2' = max(v2, min(v1,w))
// Indices: 3 exact fp32 compares + 5 selects. NO value approximation --
// R10/R15 proved index selection needs full fp32 resolution of W.
__device__ inline void ins3(float w, int idx, float v[3], int id[3]) {
  bool c0 = w > v[0], c1 = w > v[1], c2 = w > v[2];
  int n0 = c0 ? idx : id[0];
  int n1 = c0 ? id[0] : (c1 ? idx : id[1]);
  int n2 = c1 ? id[1] : (c2 ? idx : id[2]);
  id[0] = n0; id[1] = n1; id[2] = n2;
  float nv2 = fmaxf(v[2], fminf(v[1], w));       // min3(v0,v1,w) == min(v1,w) since v1<=v0
  float nv1 = __builtin_amdgcn_fmed3f(v[0], v[1], w);
  v[0] = fmaxf(v[0], w);
  v[1] = nv1; v[2] = nv2;
}

// Expand fp32 inputs into dedup'd split-bf16 panel layout (hi|lo), ctx and main.
__global__ __launch_bounds__(256) void split_convert(const float* __restrict__ ctx,
    const float* __restrict__ mn, u16* __restrict__ ctxS, u16* __restrict__ mnS) {
  const int b = blockIdx.y;
  const int rp = blockIdx.x & 15, og = blockIdx.x >> 4;  // og 0..7
  const int tid = threadIdx.x;
  const int row = tid & 127;
  const int o = og * 2 + (tid >> 7);                     // source k-octet 0..15
  const size_t srcOff = (((size_t)b * LDIM + rp * 128 + row) * DDIM + o * 8);
  const float4 c0 = *(const float4*)(ctx + srcOff);
  const float4 c1 = *(const float4*)(ctx + srcOff + 4);
  const float4 m0 = *(const float4*)(mn + srcOff);
  const float4 m1 = *(const float4*)(mn + srcOff + 4);
  uint4 chi = make_uint4(pk2(c0.x,c0.y), pk2(c0.z,c0.w), pk2(c1.x,c1.y), pk2(c1.z,c1.w));
  uint4 clo = make_uint4(pk2(c0.x-bfhi(c0.x), c0.y-bfhi(c0.y)),
                         pk2(c0.z-bfhi(c0.z), c0.w-bfhi(c0.w)),
                         pk2(c1.x-bfhi(c1.x), c1.y-bfhi(c1.y)),
                         pk2(c1.z-bfhi(c1.z), c1.w-bfhi(c1.w)));
  uint4 mhi = make_uint4(pk2(m0.x,m0.y), pk2(m0.z,m0.w), pk2(m1.x,m1.y), pk2(m1.z,m1.w));
  uint4 mlo = make_uint4(pk2(m0.x-bfhi(m0.x), m0.y-bfhi(m0.y)),
                         pk2(m0.z-bfhi(m0.z), m0.w-bfhi(m0.w)),
                         pk2(m1.x-bfhi(m1.x), m1.y-bfhi(m1.y)),
                         pk2(m1.z-bfhi(m1.z), m1.w-bfhi(m1.w)));
  u16* dA = ctxS + ((size_t)b * 16 + rp) * PANEL_U16;
  u16* dB = mnS  + ((size_t)b * 16 + rp) * PANEL_U16;
  const int base = o * 1024 + row * 8;
  *(uint4*)(dA + base)         = chi;   // koct o      : AH
  *(uint4*)(dA + base + 16384) = clo;   // koct o + 16 : AL
  *(uint4*)(dB + base)         = mhi;   // koct o      : BH
  *(uint4*)(dB + base + 16384) = mlo;   // koct o + 16 : BL
}

// W[b][c][m] = ctx.main^T via dedup'd split-bf16 MFMA. W is NEVER stored.
// Main loop: 4 chunks of 32-K; per chunk stage AH/AL/BH/BL (8KB each).
// MFMAs sequenced j-outer (aH/aL resident, bH/bL streamed) to cap fragment
// liveness at 40 VGPR; per-acc-element add order is bitwise identical to the
// i-outer form. __launch_bounds__(256,4) caps regs at 128 (64 VGPR + 64 AGPR)
// -> 4 waves/SIMD (vs 2 at the 152-reg allocation).
// Epilogue (R12-proven): quadrants staged to 64x65 LDS, whole-wave serial walks.
__global__ __launch_bounds__(256, 4) void gemm_mfma(const u16* __restrict__ A,
    const u16* __restrict__ B, unsigned* __restrict__ rowP,
    unsigned* __restrict__ colP) {
  __shared__ __attribute__((aligned(16))) char ldsbuf[33280];
  u16* AsH = (u16*)ldsbuf;           // 8 KB (4 kocts)
  u16* AsL = AsH + 4096;             // 8 KB
  u16* BsH = AsH + 8192;             // 8 KB
  u16* BsL = AsH + 12288;            // 8 KB
  float* stg = (float*)ldsbuf;       // epilogue: 2 x 4160 floats (64x65 each)
  const int b = blockIdx.z;
  const int rp = blockIdx.y, mp = blockIdx.x;
  const int tid = threadIdx.x;
  const int w = tid >> 6, lane = tid & 63;
  const int lr = lane & 15, lg = lane >> 4;
  const int wr = w >> 1, wc = w & 1;
  const u16* srcA = A + ((size_t)b * 16 + rp) * PANEL_U16;
  const u16* srcB = B + ((size_t)b * 16 + mp) * PANEL_U16;
  f32x4 acc[4][4];
  const f32x4 zz = {0.f, 0.f, 0.f, 0.f};
  #pragma unroll
  for (int i = 0; i < 4; i++)
    #pragma unroll
    for (int j = 0; j < 4; j++) acc[i][j] = zz;

  for (int ch = 0; ch < 4; ch++) {       // 32-K chunk = kocts ch*4..ch*4+3
    if (ch) __syncthreads();
    const int co = ch * 4096;            // u16 offset of chunk in H half
    #pragma unroll
    for (int q = 0; q < 2; q++) {
      const int c = q * 256 + w * 64;    // chunk-of-16B index base for this wave
      glds16(srcA + co         + (size_t)(c + lane) * 8, AsH + c * 8);
      glds16(srcA + 16384 + co + (size_t)(c + lane) * 8, AsL + c * 8);
      glds16(srcB + co         + (size_t)(c + lane) * 8, BsH + c * 8);
      glds16(srcB + 16384 + co + (size_t)(c + lane) * 8, BsL + c * 8);
    }
    __syncthreads();
    const int ao = lg * 1024 + (wr * 64 + lr) * 8;
    const int bo = lg * 1024 + (wc * 64 + lr) * 8;
    bf16x8 aH[4], aL[4];
    #pragma unroll
    for (int i = 0; i < 4; i++) aH[i] = *(const bf16x8*)&AsH[ao + i * 128];
    #pragma unroll
    for (int i = 0; i < 4; i++) aL[i] = *(const bf16x8*)&AsL[ao + i * 128];
    #pragma unroll
    for (int j = 0; j < 4; j++) {
      bf16x8 bHj = *(const bf16x8*)&BsH[bo + j * 128];
      #pragma unroll
      for (int i = 0; i < 4; i++)
        acc[i][j] = __builtin_amdgcn_mfma_f32_16x16x32_bf16(aH[i], bHj, acc[i][j], 0, 0, 0);
      #pragma unroll
      for (int i = 0; i < 4; i++)
        acc[i][j] = __builtin_amdgcn_mfma_f32_16x16x32_bf16(aL[i], bHj, acc[i][j], 0, 0, 0);
      bf16x8 bLj = *(const bf16x8*)&BsL[bo + j * 128];
      #pragma unroll
      for (int i = 0; i < 4; i++)
        acc[i][j] = __builtin_amdgcn_mfma_f32_16x16x32_bf16(aH[i], bLj, acc[i][j], 0, 0, 0);
    }
  }

  // ---- fused stats epilogue. C/D layout (m89, verified by R1 W-store):
  //      local row = i*16 + lg*4 + r, local col = j*16 + lr (within 64x64 quadrant).
  for (int rnd = 0; rnd < 2; rnd++) {
    __syncthreads();                       // main-loop LDS (or prev round stg) dead
    if (wr == rnd) {
      float* st = stg + wc * 4160;
      #pragma unroll
      for (int i = 0; i < 4; i++)
        #pragma unroll
        for (int r = 0; r < 4; r++) {
          const int row = i * 16 + lg * 4 + r;
          #pragma unroll
          for (int j = 0; j < 4; j++)
            st[row * 65 + j * 16 + lr] = acc[i][j][r];
        }
    }
    __syncthreads();
    {
      const int buf = tid >> 7;            // which staging buffer (== wc)
      const int role = (tid >> 6) & 1;     // 0: col reduce, 1: row reduce
      const int l6 = tid & 63;
      const float* st = stg + buf * 4160;
      float v[3] = {-3e38f,-3e38f,-3e38f}; int id[3] = {-1,-1,-1};
      float sm = 0.f, s2 = 0.f;
      if (role == 0) {
        // column l6 of this quadrant, over its 64 rows
        #pragma unroll 8
        for (int r = 0; r < 64; r++) {
          float wv = st[r * 65 + l6];
          sm += wv; s2 = fmaf(wv, wv, s2);
          ins3(wv, rp*128 + rnd*64 + r, v, id);
        }
        size_t rec = (((size_t)b*32 + rp*2 + rnd)*LDIM + mp*128 + buf*64 + l6) * 8;
        uint4 lo = make_uint4(__float_as_uint(v[0]), __float_as_uint(v[1]),
                              __float_as_uint(v[2]), __float_as_uint(sm));
        uint4 hi = make_uint4(__float_as_uint(s2), (unsigned)id[0],
                              (unsigned)id[1], (unsigned)id[2]);
        *(uint4*)(colP + rec)     = lo;
        *(uint4*)(colP + rec + 4) = hi;
      } else {
        // row l6 of this quadrant, over its 64 cols
        #pragma unroll 8
        for (int c = 0; c < 64; c++) {
          float wv = st[l6 * 65 + c];
          sm += wv; s2 = fmaf(wv, wv, s2);
          ins3(wv, mp*128 + buf*64 + c, v, id);
        }
        size_t rec = (((size_t)b*32 + mp*2 + buf)*LDIM + rp*128 + rnd*64 + l6) * 8;
        uint4 lo = make_uint4(__float_as_uint(v[0]), __float_as_uint(v[1]),
                              __float_as_uint(v[2]), __float_as_uint(sm));
        uint4 hi = make_uint4(__float_as_uint(s2), (unsigned)id[0],
                              (unsigned)id[1], (unsigned)id[2]);
        *(uint4*)(rowP + rec)     = lo;
        *(uint4*)(rowP + rec + 4) = hi;
      }
    }
  }
}

// Merge 32 per-tile partials per index; z=0 -> row stats, z=1 -> col stats.
__global__ __launch_bounds__(256) void stats_combine(const unsigned* __restrict__ rowP,
    const unsigned* __restrict__ colP,
    float* __restrict__ rw, int* __restrict__ ri, float* __restrict__ rs,
    float* __restrict__ cw, int* __restrict__ ci, float* __restrict__ cs) {
  const int b = blockIdx.y;
  const int c = blockIdx.x * 256 + threadIdx.x;
  const unsigned* P = blockIdx.z == 0 ? rowP : colP;
  float* w3 = blockIdx.z == 0 ? rw : cw;
  int*   i3 = blockIdx.z == 0 ? ri : ci;
  float* sd = blockIdx.z == 0 ? rs : cs;
  float v[3] = {-3e38f,-3e38f,-3e38f}; int id[3] = {-1,-1,-1};
  float sum = 0.f, sq = 0.f;
  for (int t = 0; t < 32; t++) {
    const unsigned* rec = P + (((size_t)b*32 + t)*LDIM + c) * 8;
    const uint4 lo = *(const uint4*)rec;
    const uint4 hi = *(const uint4*)(rec + 4);
    ins3(__uint_as_float(lo.x), (int)hi.y, v, id);
    ins3(__uint_as_float(lo.y), (int)hi.z, v, id);
    ins3(__uint_as_float(lo.z), (int)hi.w, v, id);
    sum += __uint_as_float(lo.w); sq += __uint_as_float(hi.x);
  }
  float inv = 1.f/(v[0]+v[1]+v[2]);
  size_t o = (size_t)b*LDIM + c;
  w3[o*3+0]=v[0]*inv; w3[o*3+1]=v[1]*inv; w3[o*3+2]=v[2]*inv;
  i3[o*3+0]=id[0]; i3[o*3+1]=id[1]; i3[o*3+2]=id[2];
  float mean = sum * (1.f/LDIM);
  float var = sq*(1.f/LDIM) - mean*mean;
  sd[o] = sqrtf(fmaxf(var, 0.f));
}

// att_merge_c[m][d] += wk_c[c][m] * ctx[c][d]  -- 3 targets per row c (scatter).
__global__ __launch_bounds__(128) void scatter_att(const float* __restrict__ ctx,
    const float* __restrict__ rw, const int* __restrict__ ri,
    float* __restrict__ attC) {
  const int b = blockIdx.y, c = blockIdx.x, d = threadIdx.x;
  const size_t base = (size_t)b*LDIM + c;
  const float x = ctx[base*DDIM + d];
  #pragma unroll
  for (int t = 0; t < 3; t++) {
    float w = rw[base*3 + t];
    int m = ri[base*3 + t];
    atomicAdd(&attC[((size_t)b*LDIM + m)*DDIM + d], w*x);
  }
}

// Convert conv weights to bf16 panel wB[ko 0..47][f 0..111][e 0..7]:
// wB[ko][f][e] = w[ks = ko/16][d = (ko%16)*8 + e][f], f >= FDIM -> 0.
__global__ __launch_bounds__(256) void conv_prep_w(const float* __restrict__ wv,
    u16* __restrict__ wB) {
  int idx = blockIdx.x * 256 + threadIdx.x;
  if (idx >= 48 * FPAD * 8) return;
  int e = idx & 7, f = (idx >> 3) % FPAD, ko = idx / (FPAD * 8);
  int ks = ko >> 4, d = ((ko & 15) << 3) | e;
  float val = (f < FDIM) ? wv[(ks * DDIM + d) * FDIM + f] : 0.f;
  wB[idx] = (u16)f2bfu(val);
}

// FUSED make_outputs + conv1d(KS=3) + bias + relu + maxpool (MFMA GEMM).
// The conv block computes its own 66 X-rows directly into the swizzled LDS tile:
//   z=0: X[t][d] = |ctx[t][d] - sum_k cw[t,k]*mn[ci[t,k]][d]| * rs[t]   (outputs_c)
//   z=1: X[t][d] = |mn[t][d] - attC[t][d]| * cs[t]                      (outputs_m)
// No global outC/outM buffers. Halo rows (2/64) recomputed. Per-row scalars are
// wave-uniform broadcasts. Then 12 MFMA/f-tile over K=384 as before.
__global__ __launch_bounds__(256) void conv_mfma(const float* __restrict__ ctx,
    const float* __restrict__ mn, const float* __restrict__ attC,
    const float* __restrict__ rs, const float* __restrict__ cw,
    const int* __restrict__ ci, const float* __restrict__ cs,
    const u16* __restrict__ wB, const float* __restrict__ bias,
    float* __restrict__ out) {
  const int b = blockIdx.y, z = blockIdx.z;
  const int t0 = blockIdx.x * CT;
  __shared__ u16 Xs[(CT + 2) * 128];   // rows of 256B, XOR-swizzled
  __shared__ float smax[FPAD];
  const int tid = threadIdx.x;
  for (int e = tid; e < (CT + 2) * 64; e += 256) {
    int row = e >> 6, p = e & 63;      // p = float2-pair index 0..63
    int t = t0 + row;
    int d2 = p * 2;
    float x0 = 0.f, x1 = 0.f;
    if (t < LDIM) {
      const size_t base = (size_t)b * LDIM + t;
      if (z == 0) {
        const float2 cx = *(const float2*)&ctx[base * DDIM + d2];
        float am0 = 0.f, am1 = 0.f;
        #pragma unroll
        for (int k = 0; k < 3; k++) {
          float wv = cw[base * 3 + k];
          const float2 g = *(const float2*)&mn[((size_t)b * LDIM + ci[base * 3 + k]) * DDIM + d2];
          am0 += wv * g.x; am1 += wv * g.y;
        }
        const float rsv = rs[base];
        x0 = fabsf(cx.x - am0) * rsv; x1 = fabsf(cx.y - am1) * rsv;
      } else {
        const float2 mm = *(const float2*)&mn[base * DDIM + d2];
        const float2 ac = *(const float2*)&attC[base * DDIM + d2];
        const float csv = cs[base];
        x0 = fabsf(mm.x - ac.x) * csv; x1 = fabsf(mm.y - ac.y) * csv;
      }
    }
    int c16 = p >> 2, q4 = p & 3;
    int byte = row * 256 + ((c16 * 16) ^ ((row & 7) << 4)) + q4 * 4;
    *(unsigned*)((char*)Xs + byte) = pk2(x0, x1);
  }
  if (tid < FPAD) smax[tid] = 0.f;
  __syncthreads();
  const int w = tid >> 6, lane = tid & 63;
  const int lr = lane & 15, lg = lane >> 4;
  const int lt0 = w * 16;
  bf16x8 av[12];
  #pragma unroll
  for (int kk = 0; kk < 12; kk++) {
    int ko = kk * 4 + lg;          // k-octet 0..47; k = ko*8+e
    int ks = ko >> 4, d8 = ko & 15;
    int row = lt0 + lr + ks;
    int byte = row * 256 + ((d8 * 16) ^ ((row & 7) << 4));
    av[kk] = *(const bf16x8*)((const char*)Xs + byte);
  }
  for (int ft = 0; ft < 7; ft++) {
    f32x4 acc = {0.f, 0.f, 0.f, 0.f};
    #pragma unroll
    for (int kk = 0; kk < 12; kk++) {
      int ko = kk * 4 + lg;
      bf16x8 bv = *(const bf16x8*)&wB[((size_t)ko * FPAD + ft * 16 + lr) * 8];
      acc = __builtin_amdgcn_mfma_f32_16x16x32_bf16(av[kk], bv, acc, 0, 0, 0);
    }
    int f = ft * 16 + lr;
    float bb = (f < FDIM) ? bias[f] : 0.f;
    float mx = 0.f;
    #pragma unroll
    for (int r = 0; r < 4; r++) {
      int t = t0 + lt0 + lg * 4 + r;
      float y = fmaxf(acc[r] + bb, 0.f);
      if (t <= LDIM - 3) mx = fmaxf(mx, y);   // invalid t -> 0 (safe: relu-max >= 0)
    }
    mx = fmaxf(mx, __shfl_xor(mx, 16));
    mx = fmaxf(mx, __shfl_xor(mx, 32));
    if (lg == 0 && f < FDIM)
      atomicMax((unsigned*)&smax[f], __float_as_uint(mx));
  }
  __syncthreads();
  if (tid < FDIM)
    atomicMax((unsigned*)&out[(size_t)b * (2 * FDIM) + z * FDIM + tid],
              __float_as_uint(smax[tid]));
}

extern "C" void kernel_launch(void* const* d_in, const int* in_sizes, int n_in,
                              void* d_out, int out_size, void* d_ws, size_t ws_size,
                              hipStream_t stream) {
  const float* ctx   = (const float*)d_in[0];
  const float* mn    = (const float*)d_in[1];
  const float* wconv = (const float*)d_in[2];
  const float* bias  = (const float*)d_in[3];
  float* out = (float*)d_out;

  // pool accumulators must start at 0 (d_out is poisoned before every call)
  hipMemsetAsync(d_out, 0, sizeof(float)*(size_t)out_size, stream);

  // Workspace: [wB bf16 weight panel: 64K floats reserved] then per-iteration arrays.
  const size_t wbFloats = 65536;
  // Per-batch (floats/dwords) -- W, outC, outM never materialized:
  //   row partial records:  32*L*8     = 524288
  //   col partial records:  32*L*8     = 524288
  //   final stats:          14*L       = 28672
  //   attC:                 L*D        = 262144
  //   split-bf16 panels:    2*16*PANEL_U16/2 = 524288
  const size_t perBatchFloats = (size_t)32*LDIM*8 + (size_t)32*LDIM*8
                              + 14*(size_t)LDIM + (size_t)LDIM*DDIM
                              + 2*(size_t)16*PANEL_U16/2;
  const size_t perBatchBytes = perBatchFloats * sizeof(float);
  int nbMax = (int)((ws_size - wbFloats*sizeof(float)) / perBatchBytes);
  if (nbMax < 1) nbMax = 1;
  if (nbMax > BDIM) nbMax = BDIM;

  u16* wB = (u16*)d_ws;
  float* iterBase = (float*)d_ws + wbFloats;
  conv_prep_w<<<dim3((48*FPAD*8 + 255)/256), 256, 0, stream>>>(wconv, wB);

  for (int b0 = 0; b0 < BDIM; b0 += nbMax) {
    const int nb = (BDIM - b0 < nbMax) ? (BDIM - b0) : nbMax;
    unsigned* rowP = (unsigned*)iterBase;
    unsigned* colP = rowP + (size_t)nb*32*LDIM*8;
    float* rowW = (float*)(colP + (size_t)nb*32*LDIM*8);
    int*   rowI = (int*)(rowW + (size_t)nb*LDIM*3);
    float* rowS = (float*)(rowI + (size_t)nb*LDIM*3);
    float* colW = rowS + (size_t)nb*LDIM;
    int*   colI = (int*)(colW + (size_t)nb*LDIM*3);
    float* colS = (float*)(colI + (size_t)nb*LDIM*3);
    float* attC = colS + (size_t)nb*LDIM;
    u16*   ctxS = (u16*)(attC + (size_t)nb*LDIM*DDIM);
    u16*   mnS  = ctxS + (size_t)nb*16*PANEL_U16;
    const float* ctxb = ctx + (size_t)b0*LDIM*DDIM;
    const float* mnb  = mn  + (size_t)b0*LDIM*DDIM;

    split_convert<<<dim3(128, nb), 256, 0, stream>>>(ctxb, mnb, ctxS, mnS);
    gemm_mfma<<<dim3(LDIM/128, LDIM/128, nb), 256, 0, stream>>>(
        ctxS, mnS, rowP, colP);
    stats_combine<<<dim3(LDIM/256, nb, 2), 256, 0, stream>>>(
        rowP, colP, rowW, rowI, rowS, colW, colI, colS);
    hipMemsetAsync(attC, 0, (size_t)nb*LDIM*DDIM*sizeof(float), stream);
    scatter_att<<<dim3(LDIM, nb), 128, 0, stream>>>(ctxb, rowW, rowI, attC);
    conv_mfma<<<dim3(LDIM/CT, nb, 2), 256, 0, stream>>>(
        ctxb, mnb, attC, rowS, colW, colI, colS, wB, bias, out + (size_t)b0*2*FDIM);
  }
}

// Round 20
// 241.368 us; speedup vs baseline: 1.4976x; 1.0938x over previous
//
#include <hip/hip_runtime.h>
#include <math.h>

#define LDIM 2048
#define DDIM 128
#define BDIM 16
#define FDIM 100
// Split-K bf16 GEMM, dedup'd panels: A' = [AH | AL], B' = [BH | BL] (K=256 stored).
// Per 32-K chunk the 3 Markidis products are computed explicitly:
//   acc += AH.BH + AL.BH + AH.BL   (== fp32 ctx.main^T to ~1e-4)
// Panel layout per (batch,row-panel): [32 koct][128 row][8 elems] bf16.
#define PANEL_U16 (32 * 1024)
// conv-as-GEMM: K = 3*128 = 384, N = 112 (100 filters padded to 7 tiles of 16)
#define FPAD 112
#define CT 64            // t-rows per conv block
#define ACAP 64          // per-target attention contribution list capacity

typedef unsigned short u16;
typedef __bf16 bf16x8 __attribute__((ext_vector_type(8)));
typedef float f32x4 __attribute__((ext_vector_type(4)));

__device__ inline unsigned f2bfu(float x) {  // fp32 -> bf16 bits, RNE
  unsigned u = __float_as_uint(x);
  return (u + 0x7FFFu + ((u >> 16) & 1u)) >> 16;
}
__device__ inline unsigned pk2(float a, float b) {
  return f2bfu(a) | (f2bfu(b) << 16);
}
__device__ inline float bfhi(float x) {  // value of the bf16 hi part
  return __uint_as_float(f2bfu(x) << 16);
}

__device__ inline void glds16(const u16* g, u16* l) {
  __builtin_amdgcn_global_load_lds(
      (const __attribute__((address_space(1))) void*)g,
      (__attribute__((address_space(3))) void*)l, 16, 0, 0);
}

// Exact top-3 insert, med3-accelerated. Values (4 ops, exact fp32):
//   v0' = max(v0,w); v1' = med3(v0,v1,w); v2' = max(v2, min(v1,w))
// Indices: 3 exact fp32 compares + 5 selects. NO value approximation --
// R10/R15 proved index selection needs full fp32 resolution of W.
__device__ inline void ins3(float w, int idx, float v[3], int id[3]) {
  bool c0 = w > v[0], c1 = w > v[1], c2 = w > v[2];
  int n0 = c0 ? idx : id[0];
  int n1 = c0 ? id[0] : (c1 ? idx : id[1]);
  int n2 = c1 ? id[1] : (c2 ? idx : id[2]);
  id[0] = n0; id[1] = n1; id[2] = n2;
  float nv2 = fmaxf(v[2], fminf(v[1], w));       // min3(v0,v1,w) == min(v1,w) since v1<=v0
  float nv1 = __builtin_amdgcn_fmed3f(v[0], v[1], w);
  v[0] = fmaxf(v[0], w);
  v[1] = nv1; v[2] = nv2;
}

// Expand fp32 inputs into dedup'd split-bf16 panel layout (hi|lo), ctx and main.
__global__ __launch_bounds__(256) void split_convert(const float* __restrict__ ctx,
    const float* __restrict__ mn, u16* __restrict__ ctxS, u16* __restrict__ mnS) {
  const int b = blockIdx.y;
  const int rp = blockIdx.x & 15, og = blockIdx.x >> 4;  // og 0..7
  const int tid = threadIdx.x;
  const int row = tid & 127;
  const int o = og * 2 + (tid >> 7);                     // source k-octet 0..15
  const size_t srcOff = (((size_t)b * LDIM + rp * 128 + row) * DDIM + o * 8);
  const float4 c0 = *(const float4*)(ctx + srcOff);
  const float4 c1 = *(const float4*)(ctx + srcOff + 4);
  const float4 m0 = *(const float4*)(mn + srcOff);
  const float4 m1 = *(const float4*)(mn + srcOff + 4);
  uint4 chi = make_uint4(pk2(c0.x,c0.y), pk2(c0.z,c0.w), pk2(c1.x,c1.y), pk2(c1.z,c1.w));
  uint4 clo = make_uint4(pk2(c0.x-bfhi(c0.x), c0.y-bfhi(c0.y)),
                         pk2(c0.z-bfhi(c0.z), c0.w-bfhi(c0.w)),
                         pk2(c1.x-bfhi(c1.x), c1.y-bfhi(c1.y)),
                         pk2(c1.z-bfhi(c1.z), c1.w-bfhi(c1.w)));
  uint4 mhi = make_uint4(pk2(m0.x,m0.y), pk2(m0.z,m0.w), pk2(m1.x,m1.y), pk2(m1.z,m1.w));
  uint4 mlo = make_uint4(pk2(m0.x-bfhi(m0.x), m0.y-bfhi(m0.y)),
                         pk2(m0.z-bfhi(m0.z), m0.w-bfhi(m0.w)),
                         pk2(m1.x-bfhi(m1.x), m1.y-bfhi(m1.y)),
                         pk2(m1.z-bfhi(m1.z), m1.w-bfhi(m1.w)));
  u16* dA = ctxS + ((size_t)b * 16 + rp) * PANEL_U16;
  u16* dB = mnS  + ((size_t)b * 16 + rp) * PANEL_U16;
  const int base = o * 1024 + row * 8;
  *(uint4*)(dA + base)         = chi;   // koct o      : AH
  *(uint4*)(dA + base + 16384) = clo;   // koct o + 16 : AL
  *(uint4*)(dB + base)         = mhi;   // koct o      : BH
  *(uint4*)(dB + base + 16384) = mlo;   // koct o + 16 : BL
}

// W[b][c][m] = ctx.main^T via dedup'd split-bf16 MFMA. W is NEVER stored.
// Main loop: 4 chunks of 32-K; per chunk stage AH/AL/BH/BL (8KB each).
// MFMAs sequenced j-outer (aH/aL resident, bH/bL streamed) to cap fragment
// liveness at 40 VGPR. __launch_bounds__(256,4) caps regs at 128 -> 4 waves/SIMD.
// Epilogue (R12-proven): quadrants staged to 64x65 LDS, whole-wave serial walks.
__global__ __launch_bounds__(256, 4) void gemm_mfma(const u16* __restrict__ A,
    const u16* __restrict__ B, unsigned* __restrict__ rowP,
    unsigned* __restrict__ colP) {
  __shared__ __attribute__((aligned(16))) char ldsbuf[33280];
  u16* AsH = (u16*)ldsbuf;           // 8 KB (4 kocts)
  u16* AsL = AsH + 4096;             // 8 KB
  u16* BsH = AsH + 8192;             // 8 KB
  u16* BsL = AsH + 12288;            // 8 KB
  float* stg = (float*)ldsbuf;       // epilogue: 2 x 4160 floats (64x65 each)
  const int b = blockIdx.z;
  const int rp = blockIdx.y, mp = blockIdx.x;
  const int tid = threadIdx.x;
  const int w = tid >> 6, lane = tid & 63;
  const int lr = lane & 15, lg = lane >> 4;
  const int wr = w >> 1, wc = w & 1;
  const u16* srcA = A + ((size_t)b * 16 + rp) * PANEL_U16;
  const u16* srcB = B + ((size_t)b * 16 + mp) * PANEL_U16;
  f32x4 acc[4][4];
  const f32x4 zz = {0.f, 0.f, 0.f, 0.f};
  #pragma unroll
  for (int i = 0; i < 4; i++)
    #pragma unroll
    for (int j = 0; j < 4; j++) acc[i][j] = zz;

  for (int ch = 0; ch < 4; ch++) {       // 32-K chunk = kocts ch*4..ch*4+3
    if (ch) __syncthreads();
    const int co = ch * 4096;            // u16 offset of chunk in H half
    #pragma unroll
    for (int q = 0; q < 2; q++) {
      const int c = q * 256 + w * 64;    // chunk-of-16B index base for this wave
      glds16(srcA + co         + (size_t)(c + lane) * 8, AsH + c * 8);
      glds16(srcA + 16384 + co + (size_t)(c + lane) * 8, AsL + c * 8);
      glds16(srcB + co         + (size_t)(c + lane) * 8, BsH + c * 8);
      glds16(srcB + 16384 + co + (size_t)(c + lane) * 8, BsL + c * 8);
    }
    __syncthreads();
    const int ao = lg * 1024 + (wr * 64 + lr) * 8;
    const int bo = lg * 1024 + (wc * 64 + lr) * 8;
    bf16x8 aH[4], aL[4];
    #pragma unroll
    for (int i = 0; i < 4; i++) aH[i] = *(const bf16x8*)&AsH[ao + i * 128];
    #pragma unroll
    for (int i = 0; i < 4; i++) aL[i] = *(const bf16x8*)&AsL[ao + i * 128];
    #pragma unroll
    for (int j = 0; j < 4; j++) {
      bf16x8 bHj = *(const bf16x8*)&BsH[bo + j * 128];
      #pragma unroll
      for (int i = 0; i < 4; i++)
        acc[i][j] = __builtin_amdgcn_mfma_f32_16x16x32_bf16(aH[i], bHj, acc[i][j], 0, 0, 0);
      #pragma unroll
      for (int i = 0; i < 4; i++)
        acc[i][j] = __builtin_amdgcn_mfma_f32_16x16x32_bf16(aL[i], bHj, acc[i][j], 0, 0, 0);
      bf16x8 bLj = *(const bf16x8*)&BsL[bo + j * 128];
      #pragma unroll
      for (int i = 0; i < 4; i++)
        acc[i][j] = __builtin_amdgcn_mfma_f32_16x16x32_bf16(aH[i], bLj, acc[i][j], 0, 0, 0);
    }
  }

  // ---- fused stats epilogue. C/D layout (m89, verified by R1 W-store):
  //      local row = i*16 + lg*4 + r, local col = j*16 + lr (within 64x64 quadrant).
  for (int rnd = 0; rnd < 2; rnd++) {
    __syncthreads();                       // main-loop LDS (or prev round stg) dead
    if (wr == rnd) {
      float* st = stg + wc * 4160;
      #pragma unroll
      for (int i = 0; i < 4; i++)
        #pragma unroll
        for (int r = 0; r < 4; r++) {
          const int row = i * 16 + lg * 4 + r;
          #pragma unroll
          for (int j = 0; j < 4; j++)
            st[row * 65 + j * 16 + lr] = acc[i][j][r];
        }
    }
    __syncthreads();
    {
      const int buf = tid >> 7;            // which staging buffer (== wc)
      const int role = (tid >> 6) & 1;     // 0: col reduce, 1: row reduce
      const int l6 = tid & 63;
      const float* st = stg + buf * 4160;
      float v[3] = {-3e38f,-3e38f,-3e38f}; int id[3] = {-1,-1,-1};
      float sm = 0.f, s2 = 0.f;
      if (role == 0) {
        // column l6 of this quadrant, over its 64 rows
        #pragma unroll 8
        for (int r = 0; r < 64; r++) {
          float wv = st[r * 65 + l6];
          sm += wv; s2 = fmaf(wv, wv, s2);
          ins3(wv, rp*128 + rnd*64 + r, v, id);
        }
        size_t rec = (((size_t)b*32 + rp*2 + rnd)*LDIM + mp*128 + buf*64 + l6) * 8;
        uint4 lo = make_uint4(__float_as_uint(v[0]), __float_as_uint(v[1]),
                              __float_as_uint(v[2]), __float_as_uint(sm));
        uint4 hi = make_uint4(__float_as_uint(s2), (unsigned)id[0],
                              (unsigned)id[1], (unsigned)id[2]);
        *(uint4*)(colP + rec)     = lo;
        *(uint4*)(colP + rec + 4) = hi;
      } else {
        // row l6 of this quadrant, over its 64 cols
        #pragma unroll 8
        for (int c = 0; c < 64; c++) {
          float wv = st[l6 * 65 + c];
          sm += wv; s2 = fmaf(wv, wv, s2);
          ins3(wv, mp*128 + buf*64 + c, v, id);
        }
        size_t rec = (((size_t)b*32 + mp*2 + buf)*LDIM + rp*128 + rnd*64 + l6) * 8;
        uint4 lo = make_uint4(__float_as_uint(v[0]), __float_as_uint(v[1]),
                              __float_as_uint(v[2]), __float_as_uint(sm));
        uint4 hi = make_uint4(__float_as_uint(s2), (unsigned)id[0],
                              (unsigned)id[1], (unsigned)id[2]);
        *(uint4*)(rowP + rec)     = lo;
        *(uint4*)(rowP + rec + 4) = hi;
      }
    }
  }
}

// Merge 32 per-tile partials per index; z=0 -> row stats, z=1 -> col stats.
// z=0 additionally routes the top-3 scatter: one 4B atomic per (row, t) appends
// (c,t) to the target row's list (avg 3 entries/target). Overflow (>ACAP,
// ~never on random data) falls back to direct atomicAdd into zeroed attC.
__global__ __launch_bounds__(256) void stats_combine(const unsigned* __restrict__ rowP,
    const unsigned* __restrict__ colP,
    float* __restrict__ rw, int* __restrict__ ri, float* __restrict__ rs,
    float* __restrict__ cw, int* __restrict__ ci, float* __restrict__ cs,
    unsigned* __restrict__ cnt, unsigned* __restrict__ list,
    float* __restrict__ attC, const float* __restrict__ ctx) {
  const int b = blockIdx.y;
  const int c = blockIdx.x * 256 + threadIdx.x;
  const unsigned* P = blockIdx.z == 0 ? rowP : colP;
  float* w3 = blockIdx.z == 0 ? rw : cw;
  int*   i3 = blockIdx.z == 0 ? ri : ci;
  float* sd = blockIdx.z == 0 ? rs : cs;
  float v[3] = {-3e38f,-3e38f,-3e38f}; int id[3] = {-1,-1,-1};
  float sum = 0.f, sq = 0.f;
  for (int t = 0; t < 32; t++) {
    const unsigned* rec = P + (((size_t)b*32 + t)*LDIM + c) * 8;
    const uint4 lo = *(const uint4*)rec;
    const uint4 hi = *(const uint4*)(rec + 4);
    ins3(__uint_as_float(lo.x), (int)hi.y, v, id);
    ins3(__uint_as_float(lo.y), (int)hi.z, v, id);
    ins3(__uint_as_float(lo.z), (int)hi.w, v, id);
    sum += __uint_as_float(lo.w); sq += __uint_as_float(hi.x);
  }
  float inv = 1.f/(v[0]+v[1]+v[2]);
  size_t o = (size_t)b*LDIM + c;
  w3[o*3+0]=v[0]*inv; w3[o*3+1]=v[1]*inv; w3[o*3+2]=v[2]*inv;
  i3[o*3+0]=id[0]; i3[o*3+1]=id[1]; i3[o*3+2]=id[2];
  float mean = sum * (1.f/LDIM);
  float var = sq*(1.f/LDIM) - mean*mean;
  sd[o] = sqrtf(fmaxf(var, 0.f));
  if (blockIdx.z == 0) {
    #pragma unroll
    for (int t = 0; t < 3; t++) {
      int m = id[t];
      unsigned pos = atomicAdd(&cnt[(size_t)b*LDIM + m], 1u);
      if (pos < ACAP) {
        list[((size_t)b*LDIM + m)*ACAP + pos] = (unsigned)(c*4 + t);
      } else {
        float wv = v[t]*inv;
        for (int d = 0; d < DDIM; d++)
          atomicAdd(&attC[((size_t)b*LDIM + m)*DDIM + d],
                    wv * ctx[((size_t)b*LDIM + c)*DDIM + d]);
      }
    }
  }
}

// attC[m][d] = sum over listed (c,t): rw[c,t] * ctx[c][d]. No atomics
// (plain accumulate on top of the overflow-only initial value).
__global__ __launch_bounds__(128) void gather_att(const float* __restrict__ ctx,
    const float* __restrict__ rw, const unsigned* __restrict__ cnt,
    const unsigned* __restrict__ list, float* __restrict__ attC) {
  const int b = blockIdx.y, m = blockIdx.x, d = threadIdx.x;
  const size_t base = (size_t)b*LDIM + m;
  unsigned n = cnt[base];
  if (n > ACAP) n = ACAP;
  float acc = attC[base*DDIM + d];
  for (unsigned e = 0; e < n; e++) {
    unsigned pk = list[base*ACAP + e];
    int c = pk >> 2, t = pk & 3;
    acc += rw[((size_t)b*LDIM + c)*3 + t] * ctx[((size_t)b*LDIM + c)*DDIM + d];
  }
  attC[base*DDIM + d] = acc;
}

// Convert conv weights to bf16 panel wB[ko 0..47][f 0..111][e 0..7]:
// wB[ko][f][e] = w[ks = ko/16][d = (ko%16)*8 + e][f], f >= FDIM -> 0.
__global__ __launch_bounds__(256) void conv_prep_w(const float* __restrict__ wv,
    u16* __restrict__ wB) {
  int idx = blockIdx.x * 256 + threadIdx.x;
  if (idx >= 48 * FPAD * 8) return;
  int e = idx & 7, f = (idx >> 3) % FPAD, ko = idx / (FPAD * 8);
  int ks = ko >> 4, d = ((ko & 15) << 3) | e;
  float val = (f < FDIM) ? wv[(ks * DDIM + d) * FDIM + f] : 0.f;
  wB[idx] = (u16)f2bfu(val);
}

// FUSED make_outputs + conv1d(KS=3) + bias + relu + maxpool (MFMA GEMM).
// The conv block computes its own 66 X-rows directly into the swizzled LDS tile:
//   z=0: X[t][d] = |ctx[t][d] - sum_k cw[t,k]*mn[ci[t,k]][d]| * rs[t]   (outputs_c)
//   z=1: X[t][d] = |mn[t][d] - attC[t][d]| * cs[t]                      (outputs_m)
__global__ __launch_bounds__(256) void conv_mfma(const float* __restrict__ ctx,
    const float* __restrict__ mn, const float* __restrict__ attC,
    const float* __restrict__ rs, const float* __restrict__ cw,
    const int* __restrict__ ci, const float* __restrict__ cs,
    const u16* __restrict__ wB, const float* __restrict__ bias,
    float* __restrict__ out) {
  const int b = blockIdx.y, z = blockIdx.z;
  const int t0 = blockIdx.x * CT;
  __shared__ u16 Xs[(CT + 2) * 128];   // rows of 256B, XOR-swizzled
  __shared__ float smax[FPAD];
  const int tid = threadIdx.x;
  for (int e = tid; e < (CT + 2) * 64; e += 256) {
    int row = e >> 6, p = e & 63;      // p = float2-pair index 0..63
    int t = t0 + row;
    int d2 = p * 2;
    float x0 = 0.f, x1 = 0.f;
    if (t < LDIM) {
      const size_t base = (size_t)b * LDIM + t;
      if (z == 0) {
        const float2 cx = *(const float2*)&ctx[base * DDIM + d2];
        float am0 = 0.f, am1 = 0.f;
        #pragma unroll
        for (int k = 0; k < 3; k++) {
          float wv = cw[base * 3 + k];
          const float2 g = *(const float2*)&mn[((size_t)b * LDIM + ci[base * 3 + k]) * DDIM + d2];
          am0 += wv * g.x; am1 += wv * g.y;
        }
        const float rsv = rs[base];
        x0 = fabsf(cx.x - am0) * rsv; x1 = fabsf(cx.y - am1) * rsv;
      } else {
        const float2 mm = *(const float2*)&mn[base * DDIM + d2];
        const float2 ac = *(const float2*)&attC[base * DDIM + d2];
        const float csv = cs[base];
        x0 = fabsf(mm.x - ac.x) * csv; x1 = fabsf(mm.y - ac.y) * csv;
      }
    }
    int c16 = p >> 2, q4 = p & 3;
    int byte = row * 256 + ((c16 * 16) ^ ((row & 7) << 4)) + q4 * 4;
    *(unsigned*)((char*)Xs + byte) = pk2(x0, x1);
  }
  if (tid < FPAD) smax[tid] = 0.f;
  __syncthreads();
  const int w = tid >> 6, lane = tid & 63;
  const int lr = lane & 15, lg = lane >> 4;
  const int lt0 = w * 16;
  bf16x8 av[12];
  #pragma unroll
  for (int kk = 0; kk < 12; kk++) {
    int ko = kk * 4 + lg;          // k-octet 0..47; k = ko*8+e
    int ks = ko >> 4, d8 = ko & 15;
    int row = lt0 + lr + ks;
    int byte = row * 256 + ((d8 * 16) ^ ((row & 7) << 4));
    av[kk] = *(const bf16x8*)((const char*)Xs + byte);
  }
  for (int ft = 0; ft < 7; ft++) {
    f32x4 acc = {0.f, 0.f, 0.f, 0.f};
    #pragma unroll
    for (int kk = 0; kk < 12; kk++) {
      int ko = kk * 4 + lg;
      bf16x8 bv = *(const bf16x8*)&wB[((size_t)ko * FPAD + ft * 16 + lr) * 8];
      acc = __builtin_amdgcn_mfma_f32_16x16x32_bf16(av[kk], bv, acc, 0, 0, 0);
    }
    int f = ft * 16 + lr;
    float bb = (f < FDIM) ? bias[f] : 0.f;
    float mx = 0.f;
    #pragma unroll
    for (int r = 0; r < 4; r++) {
      int t = t0 + lt0 + lg * 4 + r;
      float y = fmaxf(acc[r] + bb, 0.f);
      if (t <= LDIM - 3) mx = fmaxf(mx, y);   // invalid t -> 0 (safe: relu-max >= 0)
    }
    mx = fmaxf(mx, __shfl_xor(mx, 16));
    mx = fmaxf(mx, __shfl_xor(mx, 32));
    if (lg == 0 && f < FDIM)
      atomicMax((unsigned*)&smax[f], __float_as_uint(mx));
  }
  __syncthreads();
  if (tid < FDIM)
    atomicMax((unsigned*)&out[(size_t)b * (2 * FDIM) + z * FDIM + tid],
              __float_as_uint(smax[tid]));
}

extern "C" void kernel_launch(void* const* d_in, const int* in_sizes, int n_in,
                              void* d_out, int out_size, void* d_ws, size_t ws_size,
                              hipStream_t stream) {
  const float* ctx   = (const float*)d_in[0];
  const float* mn    = (const float*)d_in[1];
  const float* wconv = (const float*)d_in[2];
  const float* bias  = (const float*)d_in[3];
  float* out = (float*)d_out;

  // pool accumulators must start at 0 (d_out is poisoned before every call)
  hipMemsetAsync(d_out, 0, sizeof(float)*(size_t)out_size, stream);

  // Workspace: [wB bf16 weight panel: 64K floats reserved] then per-iteration arrays.
  const size_t wbFloats = 65536;
  // Per-batch (floats/dwords) -- W, outC, outM never materialized:
  //   row partial records:  32*L*8       = 524288
  //   col partial records:  32*L*8       = 524288
  //   final stats:          14*L         = 28672
  //   attC:                 L*D          = 262144
  //   att lists:            L*(ACAP+1)   = 133120
  //   split-bf16 panels:    2*16*PANEL_U16/2 = 524288
  const size_t perBatchFloats = (size_t)32*LDIM*8 + (size_t)32*LDIM*8
                              + 14*(size_t)LDIM + (size_t)LDIM*DDIM
                              + (size_t)LDIM*(ACAP+1)
                              + 2*(size_t)16*PANEL_U16/2;
  const size_t perBatchBytes = perBatchFloats * sizeof(float);
  int nbMax = (int)((ws_size - wbFloats*sizeof(float)) / perBatchBytes);
  if (nbMax < 1) nbMax = 1;
  if (nbMax > BDIM) nbMax = BDIM;

  u16* wB = (u16*)d_ws;
  float* iterBase = (float*)d_ws + wbFloats;
  conv_prep_w<<<dim3((48*FPAD*8 + 255)/256), 256, 0, stream>>>(wconv, wB);

  for (int b0 = 0; b0 < BDIM; b0 += nbMax) {
    const int nb = (BDIM - b0 < nbMax) ? (BDIM - b0) : nbMax;
    unsigned* rowP = (unsigned*)iterBase;
    unsigned* colP = rowP + (size_t)nb*32*LDIM*8;
    float* rowW = (float*)(colP + (size_t)nb*32*LDIM*8);
    int*   rowI = (int*)(rowW + (size_t)nb*LDIM*3);
    float* rowS = (float*)(rowI + (size_t)nb*LDIM*3);
    float* colW = rowS + (size_t)nb*LDIM;
    int*   colI = (int*)(colW + (size_t)nb*LDIM*3);
    float* colS = (float*)(colI + (size_t)nb*LDIM*3);
    float* attC = colS + (size_t)nb*LDIM;
    unsigned* cntA = (unsigned*)(attC + (size_t)nb*LDIM*DDIM);
    unsigned* listA = cntA + (size_t)nb*LDIM;
    u16*   ctxS = (u16*)(listA + (size_t)nb*LDIM*ACAP);
    u16*   mnS  = ctxS + (size_t)nb*16*PANEL_U16;
    const float* ctxb = ctx + (size_t)b0*LDIM*DDIM;
    const float* mnb  = mn  + (size_t)b0*LDIM*DDIM;

    split_convert<<<dim3(128, nb), 256, 0, stream>>>(ctxb, mnb, ctxS, mnS);
    hipMemsetAsync(attC, 0, (size_t)nb*LDIM*DDIM*sizeof(float), stream);
    hipMemsetAsync(cntA, 0, (size_t)nb*LDIM*sizeof(unsigned), stream);
    gemm_mfma<<<dim3(LDIM/128, LDIM/128, nb), 256, 0, stream>>>(
        ctxS, mnS, rowP, colP);
    stats_combine<<<dim3(LDIM/256, nb, 2), 256, 0, stream>>>(
        rowP, colP, rowW, rowI, rowS, colW, colI, colS, cntA, listA, attC, ctxb);
    gather_att<<<dim3(LDIM, nb), 128, 0, stream>>>(ctxb, rowW, cntA, listA, attC);
    conv_mfma<<<dim3(LDIM/CT, nb, 2), 256, 0, stream>>>(
        ctxb, mnb, attC, rowS, colW, colI, colS, wB, bias, out + (size_t)b0*2*FDIM);
  }
}